// Round 8
// baseline (2715.653 us; speedup 1.0000x reference)
//
#include <hip/hip_runtime.h>

typedef unsigned short u16;
typedef __attribute__((ext_vector_type(8))) short short8;
typedef __attribute__((ext_vector_type(4))) float floatx4;
typedef __attribute__((ext_vector_type(4))) unsigned short ushortx4;

#define BD 4096
#define DD 2048
#define NTOT (BD*DD)
#define MAX_STEPS 3

// ---- Dopri5 tableau, exactly as jax.experimental.ode (f64 exprs -> f32) ----
#define CE0 ((float)(35.0/384.0 - 1951.0/21600.0))
#define CE2 ((float)(500.0/1113.0 - 22642.0/50085.0))
#define CE3 ((float)(125.0/192.0 - 451.0/720.0))
#define CE4 ((float)(-2187.0/6784.0 + 12231.0/42400.0))
#define CE5 ((float)(11.0/84.0 - 649.0/6300.0))
#define CE6 ((float)(-1.0/60.0))

#define CM0 ((float)(6025192743.0/30085553152.0/2.0))
#define CM2 ((float)(51252292925.0/65400821598.0/2.0))
#define CM3 ((float)(-2691868925.0/45128329728.0/2.0))
#define CM4 ((float)(187940372067.0/1594534317056.0/2.0))
#define CM5 ((float)(-1776094331.0/19743644256.0/2.0))
#define CM6 ((float)(11237099.0/235043384.0/2.0))

#define CS0 ((float)(35.0/384.0))
#define CS2 ((float)(500.0/1113.0))
#define CS3 ((float)(125.0/192.0))
#define CS4 ((float)(-2187.0/6784.0))
#define CS5 ((float)(11.0/84.0))

#define B50 ((float)(9017.0/3168.0))
#define B51 ((float)(-355.0/33.0))
#define B52 ((float)(46732.0/5247.0))
#define B53 ((float)(49.0/176.0))
#define B54 ((float)(-5103.0/18656.0))

struct Scal {
  float t, dt, last_t, h0, dt_saved;
  float d0s, d1s, d2s, errs;
  float d0, d1;
  int run_flag, accept_flag, cur;
};

__device__ __forceinline__ u16 f2bf(float x) {
  unsigned int u = __float_as_uint(x);
  u += 0x7FFFu + ((u >> 16) & 1u);     // RNE
  return (u16)(u >> 16);
}
__device__ __forceinline__ float bf2f(u16 h) {
  return __uint_as_float(((unsigned int)h) << 16);
}
__device__ __forceinline__ void splitw(float v, u16* oh, u16* ol, size_t idx) {
  u16 h = f2bf(v);
  oh[idx] = h;
  ol[idx] = f2bf(v - bf2f(h));
}
// 4-wide split: hi/lo bf16 of 4 consecutive elements, one 8B store each
__device__ __forceinline__ void splitw4(floatx4 v, u16* oh, u16* ol, size_t idx) {
  ushortx4 h, l;
  #pragma unroll
  for (int e = 0; e < 4; ++e) {
    u16 hh = f2bf(v[e]);
    h[e] = hh;
    l[e] = f2bf(v[e] - bf2f(hh));
  }
  *(ushortx4*)&oh[idx] = h;
  *(ushortx4*)&ol[idx] = l;
}
// bf16 plane helpers (8B coalesced per lane)
__device__ __forceinline__ floatx4 bf4(ushortx4 u) {
  floatx4 f;
  #pragma unroll
  for (int e = 0; e < 4; ++e) f[e] = bf2f(u[e]);
  return f;
}
__device__ __forceinline__ floatx4 load4bf(const u16* __restrict__ p, size_t idx) {
  return bf4(*(const ushortx4*)&p[idx]);
}
__device__ __forceinline__ void store4bf(u16* __restrict__ p, size_t idx, floatx4 v) {
  ushortx4 u;
  #pragma unroll
  for (int e = 0; e < 4; ++e) u[e] = f2bf(v[e]);
  *(ushortx4*)&p[idx] = u;
}

// async global->LDS DMA, 16 B per lane. LDS dest = uniform base + lane*16.
__device__ __forceinline__ void gload16(const u16* g, u16* l) {
  __builtin_amdgcn_global_load_lds(
      (const __attribute__((address_space(1))) void*)g,
      (__attribute__((address_space(3))) void*)l, 16, 0, 0);
}

// =================  weight transpose -> bf16 [N][K]  =================
__global__ void transpose_hi(const float* __restrict__ W, u16* __restrict__ th,
                             int K, int N) {
  __shared__ float tile[32][33];
  int k0 = blockIdx.x * 32, n0 = blockIdx.y * 32;
  int tx = threadIdx.x, ty = threadIdx.y;   // 32 x 8
  #pragma unroll
  for (int j = 0; j < 32; j += 8)
    tile[ty + j][tx] = W[(size_t)(k0 + ty + j) * N + n0 + tx];
  __syncthreads();
  #pragma unroll
  for (int j = 0; j < 32; j += 8) {
    int nn = ty + j, kk = tx;
    th[(size_t)(n0 + nn) * K + k0 + kk] = f2bf(tile[kk][nn]);
  }
}

// ==============  split-A bf16 MFMA GEMM, fused Dopri5 epilogues  ============
// R6 base (verified 2405us, absmax 0.03125): 64x128 tile, BK=64, grid 1024,
// LDS 64KB dbuf, counted-vmcnt pipeline, bf16 k-planes, coalesced epilogue.
// R7 (f16 A+W) FAILED absmax 0.279 -> A-side split precision is load-bearing;
// reverted, precision scheme frozen at R6.
// R8 change: T14 epilogue-stream prefetch.  Each thread's epilogue input
// addresses (F/Yc/k-planes, 8 float4/ushortx4 chunks each) are known at
// kernel start.  Issue ONE stream (8 loads) per early K-iteration, AFTER
// that iteration's stage() -- vmcnt accounting stays deterministic:
//   t <= NS: s_waitcnt vmcnt(16)  (leaves {next tile 8, newest batch 8};
//            tile t+1 is strictly older -> guaranteed complete)
//   t >  NS: s_waitcnt vmcnt(8)   (flushes last batch + tile t+1)
// The ~19us of epilogue HBM reads (96MB heavy-stage) hide under the ~45us
// K-loop; epilogue collapses to compute+stores.  All element reads still
// precede writes -> math bit-identical to R6.
template <int STAGE>
__global__ __launch_bounds__(256, 2)
void gemm_fused(const u16* __restrict__ Ah, const u16* __restrict__ Al,
                const u16* __restrict__ Bt,
                const float* __restrict__ bias, const float* __restrict__ trow,
                int tmode, float alpha_c,
                float bb0, float bb1, float bb2, float bbv,
                float* __restrict__ YA, float* __restrict__ YB,
                u16* __restrict__ FB, u16* __restrict__ KB2,
                u16* __restrict__ KB3, u16* __restrict__ KB4,
                u16* __restrict__ KB6, float* __restrict__ Mout,
                u16* __restrict__ oh, u16* __restrict__ ol,
                Scal* __restrict__ s, int flag) {
  if (flag == 1 && !s->run_flag) return;

  // one contiguous 64KB block: per buffer [Ah 4096 | Al 4096 | B 8192] u16
  __shared__ __attribute__((aligned(16))) u16 raw[2][16384];
  #define AH_OFF 0
  #define AL_OFF 4096
  #define B_OFF  8192

  const int tid = threadIdx.x;
  const int lane = tid & 63;
  const int wave = tid >> 6;

  // XCD-aware swizzle: each XCD (lin&7) owns 8 bm-strips x all 16 bn.
  const int lin = blockIdx.x;
  const int xcd = lin & 7;
  const int slot = lin >> 3;                 // 0..127
  const int bm = (xcd * 8 + (slot >> 4)) * 64;
  const int bn = (slot & 15) * 128;

  const int m_w = (wave >> 1) * 32;          // 2 M-waves x 2 N-waves
  const int n_w = (wave & 1) * 64;
  const int lr = lane & 15;

  // scalar state read up-front (needed by prefetch)
  const int cur = s->cur;
  const float* Yc = cur ? YB : YA;
  float* NY = cur ? YA : YB;
  const float dt = s->dt;
  float tj = 0.f;
  if (STAGE == 100) tj = (tmode == 0) ? (s->t + dt * alpha_c) : s->h0;

  // DMA: one instr = 8 rows x 128 B.  Lane l -> row base+(l>>3), global
  // chunk g=(l&7)^(l>>3); LDS dest base+l*16 -> swizzled pos p = l&7.
  const int lrow = lane >> 3;                       // 0..7
  const int lcol = (((lane & 7) ^ (lane >> 3)) << 3);
  const int ra = wave * 16;
  const int rb = wave * 32;
  const u16* gAh = Ah + (size_t)(bm + ra + lrow) * DD + lcol;
  const u16* gAl = Al + (size_t)(bm + ra + lrow) * DD + lcol;
  const u16* gB  = Bt + (size_t)(bn + rb + lrow) * DD + lcol;

  floatx4 acc[2][4];
  #pragma unroll
  for (int i = 0; i < 2; ++i)
    #pragma unroll
    for (int j = 0; j < 4; ++j)
      acc[i][j] = (floatx4){0.f, 0.f, 0.f, 0.f};

  // stage K-tile at k0 into buffer b (8 global_load_lds per wave)
  auto stage = [&](int k0, int b) {
    #pragma unroll
    for (int t = 0; t < 2; ++t) {
      gload16(gAh + k0 + (size_t)(8 * t) * DD, &raw[b][AH_OFF + (ra + 8 * t) * 64]);
      gload16(gAl + k0 + (size_t)(8 * t) * DD, &raw[b][AL_OFF + (ra + 8 * t) * 64]);
    }
    #pragma unroll
    for (int t = 0; t < 4; ++t)
      gload16(gB + k0 + (size_t)(8 * t) * DD, &raw[b][B_OFF + (rb + 8 * t) * 64]);
  };

  // epilogue chunk addressing (8 row-linear float4 chunks per thread)
  auto pfidx = [&](int q) -> size_t {
    const int fidx = tid + 256 * q;
    return (size_t)(bm + (fidx >> 5)) * DD + bn + ((fidx & 31) << 2);
  };

  // T14 prefetch state.  Streams per stage: 0:{F,Y} 1:{+K2} 2:{+K3}
  // 3:{+K4} 4:{F,Y,K2,K3,K4} 5:{+K6}.  One stream issued per K-iteration.
  constexpr int NS = (STAGE == 0) ? 2 : (STAGE == 1) ? 3 : (STAGE == 2) ? 4
                   : (STAGE == 3) ? 5 : (STAGE == 4) ? 5 : (STAGE == 5) ? 6 : 0;
  ushortx4 pF[8], pK2[8], pK3[8], pK4[8], pK6[8];
  floatx4 pY[8];

  // prologue: tiles 0 and 1 in flight; wait only for tile 0 (vmcnt(8))
  stage(0, 0);
  stage(64, 1);
  asm volatile("s_waitcnt vmcnt(8)" ::: "memory");
  __builtin_amdgcn_s_barrier();

  const int NT = DD / 64;              // 32 K-tiles
  int bufc = 0;
  for (int t = 0; t < NT; ++t) {
    #pragma unroll
    for (int kk = 0; kk < 2; ++kk) {   // k-slices +0 and +32
      const int cb = kk * 4 + (lane >> 4);          // global chunk 0..7
      short8 afh[2], afl[2], bfv[4];
      #pragma unroll
      for (int i = 0; i < 2; ++i) {
        int r = m_w + i * 16 + lr;
        int ar = r * 64 + ((cb ^ (lr & 7)) << 3);
        afh[i] = *(const short8*)&raw[bufc][AH_OFF + ar];
        afl[i] = *(const short8*)&raw[bufc][AL_OFF + ar];
      }
      #pragma unroll
      for (int j = 0; j < 4; ++j) {
        int r = n_w + j * 16 + lr;
        bfv[j] = *(const short8*)&raw[bufc][B_OFF + r * 64 + ((cb ^ (lr & 7)) << 3)];
      }
      #pragma unroll
      for (int i = 0; i < 2; ++i)
        #pragma unroll
        for (int j = 0; j < 4; ++j) {
          acc[i][j] = __builtin_amdgcn_mfma_f32_16x16x32_bf16(afh[i], bfv[j], acc[i][j], 0, 0, 0);
          acc[i][j] = __builtin_amdgcn_mfma_f32_16x16x32_bf16(afl[i], bfv[j], acc[i][j], 0, 0, 0);
        }
    }

    if (t < NT - 1) {
      // all waves' ds_reads of bufc complete (lgkmcnt-waited before MFMAs)
      __builtin_amdgcn_s_barrier();
      if (t < NT - 2) {
        stage((t + 2) * 64, bufc);     // overwrite consumed buffer
        if constexpr (NS > 0) {
          // issue one epilogue stream per iteration (younger than staging)
          if (t == 0) {
            #pragma unroll
            for (int q = 0; q < 8; ++q) pF[q] = *(const ushortx4*)&FB[pfidx(q)];
          }
          if (t == 1) {
            #pragma unroll
            for (int q = 0; q < 8; ++q) pY[q] = *(const floatx4*)&Yc[pfidx(q)];
          }
          if constexpr (NS >= 3) if (t == 2) {
            #pragma unroll
            for (int q = 0; q < 8; ++q) pK2[q] = *(const ushortx4*)&KB2[pfidx(q)];
          }
          if constexpr (NS >= 4) if (t == 3) {
            #pragma unroll
            for (int q = 0; q < 8; ++q) pK3[q] = *(const ushortx4*)&KB3[pfidx(q)];
          }
          if constexpr (NS >= 5) if (t == 4) {
            #pragma unroll
            for (int q = 0; q < 8; ++q) pK4[q] = *(const ushortx4*)&KB4[pfidx(q)];
          }
          if constexpr (NS >= 6) if (t == 5) {
            #pragma unroll
            for (int q = 0; q < 8; ++q) pK6[q] = *(const ushortx4*)&KB6[pfidx(q)];
          }
          if (t <= NS) {
            // leave {tile t+2 (8), newest batch (8)}; tile t+1 is older ->
            // guaranteed complete before next compute
            asm volatile("s_waitcnt vmcnt(16)" ::: "memory");
          } else {
            asm volatile("s_waitcnt vmcnt(8)" ::: "memory");
          }
        } else {
          asm volatile("s_waitcnt vmcnt(8)" ::: "memory");
        }
      } else {
        asm volatile("s_waitcnt vmcnt(0)" ::: "memory");
      }
      __builtin_amdgcn_s_barrier();    // tile t+1 visible to all waves
      bufc ^= 1;
    }
  }

  // ---- epilogue: acc -> padded LDS f32 tile -> vectorized global I/O ----
  __syncthreads();                     // staging LDS dead; vmcnt drained
  float* ep = (float*)&raw[0][0];      // 64 x 132 f32 = 33792 B (< 64 KB)
  const int oq = (lane >> 4) * 4;
  const int oc = lane & 15;
  #pragma unroll
  for (int i = 0; i < 2; ++i)
    #pragma unroll
    for (int j = 0; j < 4; ++j)
      #pragma unroll
      for (int r = 0; r < 4; ++r)
        ep[(m_w + i * 16 + oq + r) * 132 + (n_w + j * 16 + oc)] = acc[i][j][r];
  __syncthreads();

  float err_acc = 0.f;
  #pragma unroll
  for (int q = 0; q < 8; ++q) {
    const int fidx = tid + 256 * q;
    const int rl = fidx >> 5;                 // local row 0..63
    const int cl = (fidx & 31) << 2;          // local col, % 4 == 0
    const int n = bn + cl;
    const size_t idx = (size_t)(bm + rl) * DD + n;
    floatx4 v = *(const floatx4*)&ep[rl * 132 + cl];
    {
      floatx4 b4 = *(const floatx4*)&bias[n];
      #pragma unroll
      for (int e = 0; e < 4; ++e) v[e] = v[e] + b4[e];
    }
    if constexpr (STAGE == 100) {
      floatx4 t4 = *(const floatx4*)&trow[n];
      floatx4 h4;
      #pragma unroll
      for (int e = 0; e < 4; ++e) h4[e] = tanhf(v[e] + tj * t4[e]);
      splitw4(h4, oh, ol, idx);
    } else if constexpr (STAGE == 0) {           // k2
      floatx4 fv = bf4(pF[q]);
      floatx4 yv = pY[q];
      store4bf(KB2, idx, v);
      floatx4 ys;
      #pragma unroll
      for (int e = 0; e < 4; ++e)
        ys[e] = yv[e] + dt * (bb0 * fv[e] + bbv * v[e]);
      splitw4(ys, oh, ol, idx);
    } else if constexpr (STAGE == 1) {           // k3
      floatx4 fv = bf4(pF[q]);
      floatx4 yv = pY[q];
      floatx4 k2 = bf4(pK2[q]);
      store4bf(KB3, idx, v);
      floatx4 ys;
      #pragma unroll
      for (int e = 0; e < 4; ++e)
        ys[e] = yv[e] + dt * (bb0 * fv[e] + bb1 * k2[e] + bbv * v[e]);
      splitw4(ys, oh, ol, idx);
    } else if constexpr (STAGE == 2) {           // k4
      floatx4 fv = bf4(pF[q]);
      floatx4 yv = pY[q];
      floatx4 k2 = bf4(pK2[q]);
      floatx4 k3 = bf4(pK3[q]);
      store4bf(KB4, idx, v);
      floatx4 ys;
      #pragma unroll
      for (int e = 0; e < 4; ++e)
        ys[e] = yv[e] + dt * (bb0 * fv[e] + bb1 * k2[e] + bb2 * k3[e] + bbv * v[e]);
      splitw4(ys, oh, ol, idx);
    } else if constexpr (STAGE == 3) {           // k5: overwrite k2 plane
      floatx4 fv = bf4(pF[q]);
      floatx4 yv = pY[q];
      floatx4 k2 = bf4(pK2[q]);
      floatx4 k3 = bf4(pK3[q]);
      floatx4 k4 = bf4(pK4[q]);
      store4bf(KB2, idx, v);                     // k5 (k2 dead)
      floatx4 ys;
      #pragma unroll
      for (int e = 0; e < 4; ++e)
        ys[e] = yv[e] + dt * (B50 * fv[e] + B51 * k2[e] + B52 * k3[e] + B53 * k4[e] + B54 * v[e]);
      splitw4(ys, oh, ol, idx);
    } else if constexpr (STAGE == 4) {           // k6: NY + store k6
      floatx4 fv = bf4(pF[q]);
      floatx4 yv = pY[q];
      floatx4 k3 = bf4(pK3[q]);
      floatx4 k4 = bf4(pK4[q]);
      floatx4 k5 = bf4(pK2[q]);
      floatx4 ny;
      #pragma unroll
      for (int e = 0; e < 4; ++e)
        ny[e] = yv[e] + dt * (CS0 * fv[e] + CS2 * k3[e] + CS3 * k4[e] + CS4 * k5[e] + CS5 * v[e]);
      *(floatx4*)&NY[idx] = ny;
      store4bf(KB6, idx, v);
      splitw4(ny, oh, ol, idx);
    } else if constexpr (STAGE == 5) {           // k7 + E/M recompute + err
      floatx4 fv = bf4(pF[q]);
      floatx4 k3 = bf4(pK3[q]);
      floatx4 k4 = bf4(pK4[q]);
      floatx4 k5 = bf4(pK2[q]);
      floatx4 k6 = bf4(pK6[q]);
      floatx4 yv = pY[q];
      floatx4 nyv = *(const floatx4*)&NY[idx];
      floatx4 M4;
      #pragma unroll
      for (int e = 0; e < 4; ++e) {
        float Ef = CE0 * fv[e] + CE2 * k3[e] + CE3 * k4[e] + CE4 * k5[e] + CE5 * k6[e] + CE6 * v[e];
        M4[e] = CM0 * fv[e] + CM2 * k3[e] + CM3 * k4[e] + CM4 * k5[e] + CM5 * k6[e] + CM6 * v[e];
        float er = dt * Ef;
        float tol = 1.f + fmaxf(fabsf(yv[e]), fabsf(nyv[e]));
        float rr = er / tol;
        err_acc += rr * rr;
      }
      store4bf(KB4, idx, v);                     // k7 (k4 consumed above)
      *(floatx4*)&Mout[idx] = M4;
    } else if constexpr (STAGE == 10) {
      store4bf(FB, idx, v);
    } else {                                     // 11
      store4bf(KB4, idx, v);
    }
  }

  if constexpr (STAGE == 5) {
    __syncthreads();                   // ep reads done
    float* red = (float*)&raw[0][0];
    red[tid] = err_acc;
    __syncthreads();
    for (int off = 128; off > 0; off >>= 1) {
      if (tid < off) red[tid] += red[tid + off];
      __syncthreads();
    }
    if (tid == 0) atomicAdd(&s->errs, red[0]);
  }
  #undef AH_OFF
  #undef AL_OFF
  #undef B_OFF
}

// ============================  elementwise etc  =============================
__global__ void k_init_scal(Scal* s) {
  s->t = 0.f; s->dt = 0.f; s->last_t = 0.f; s->h0 = 0.f; s->dt_saved = 1.f;
  s->d0s = 0.f; s->d1s = 0.f; s->d2s = 0.f; s->errs = 0.f;
  s->d0 = 0.f; s->d1 = 0.f;
  s->run_flag = 0; s->accept_flag = 0; s->cur = 0;
}

__global__ void k_init_y(const float* __restrict__ x, float* __restrict__ y,
                         u16* __restrict__ ysh, u16* __restrict__ ysl, int n) {
  for (int i = blockIdx.x * blockDim.x + threadIdx.x; i < n; i += gridDim.x * blockDim.x) {
    float v = x[i];
    y[i] = v;
    splitw(v, ysh, ysl, i);
  }
}

// ys = y0 + h0 * f0 (heuristic probe input); f0 bf16
__global__ void k_probe_ys(const float* __restrict__ y, const u16* __restrict__ fb,
                           u16* __restrict__ ysh, u16* __restrict__ ysl, int n,
                           const Scal* __restrict__ s) {
  float h0 = s->h0;
  for (int i = blockIdx.x * blockDim.x + threadIdx.x; i < n; i += gridDim.x * blockDim.x)
    splitw(y[i] + h0 * bf2f(fb[i]), ysh, ysl, i);
}

// End-of-trial bookkeeping + next-trial first-stage input (4-wide).
// accept: KB3 = FB_old (f0save); FB = k7(KB4); Mout = Yc + dts*Mout (ymid);
//         y' = NY.  reject: y' = Yc, FB unchanged.
// Then ys2 = split(y' + dt_new*0.2*f').
__global__ void k_prep(float* YA, float* YB, u16* __restrict__ FB,
                       u16* __restrict__ KB3, const u16* __restrict__ KB4,
                       float* __restrict__ Mout,
                       u16* __restrict__ ysh, u16* __restrict__ ysl, int n4,
                       const Scal* __restrict__ s, int mode) {
  if (mode == 0 && !s->run_flag) return;
  int acc = (mode == 0) ? s->accept_flag : 0;
  int cur = s->cur;
  const float* Yc = cur ? YB : YA;
  const float* Yn = cur ? YA : YB;
  float dtn = s->dt, dts = s->dt_saved;
  for (int i = blockIdx.x * blockDim.x + threadIdx.x; i < n4; i += gridDim.x * blockDim.x) {
    size_t idx = (size_t)i * 4;
    ushortx4 fold = *(const ushortx4*)&FB[idx];
    floatx4 ys;
    if (acc) {
      ushortx4 k7 = *(const ushortx4*)&KB4[idx];
      floatx4 yn4 = *(const floatx4*)&Yn[idx];
      floatx4 yc4 = *(const floatx4*)&Yc[idx];
      floatx4 m4 = *(const floatx4*)&Mout[idx];
      *(ushortx4*)&FB[idx] = k7;
      *(ushortx4*)&KB3[idx] = fold;
      floatx4 ym;
      #pragma unroll
      for (int e = 0; e < 4; ++e) ym[e] = yc4[e] + dts * m4[e];
      *(floatx4*)&Mout[idx] = ym;
      #pragma unroll
      for (int e = 0; e < 4; ++e) ys[e] = yn4[e] + dtn * 0.2f * bf2f(k7[e]);
    } else {
      floatx4 yc4 = *(const floatx4*)&Yc[idx];
      #pragma unroll
      for (int e = 0; e < 4; ++e) ys[e] = yc4[e] + dtn * 0.2f * bf2f(fold[e]);
    }
    splitw4(ys, ysh, ysl, idx);
  }
}

__global__ void k_d01(const float* __restrict__ y, const u16* __restrict__ fb,
                      int n, Scal* s) {
  float a0 = 0.f, a1 = 0.f;
  for (int i = blockIdx.x * blockDim.x + threadIdx.x; i < n; i += gridDim.x * blockDim.x) {
    float yv = y[i], fv = bf2f(fb[i]);
    float sc = 1.f + fabsf(yv);
    float t0 = yv / sc, t1 = fv / sc;
    a0 += t0 * t0;
    a1 += t1 * t1;
  }
  __shared__ float r0[256], r1[256];
  int tid = threadIdx.x;
  r0[tid] = a0; r1[tid] = a1;
  __syncthreads();
  for (int off = 128; off > 0; off >>= 1) {
    if (tid < off) { r0[tid] += r0[tid + off]; r1[tid] += r1[tid + off]; }
    __syncthreads();
  }
  if (tid == 0) { atomicAdd(&s->d0s, r0[0]); atomicAdd(&s->d1s, r1[0]); }
}

__global__ void k_h0(Scal* s) {
  float d0 = sqrtf(s->d0s);    // 2-norm (jnp.linalg.norm), NOT rms
  float d1 = sqrtf(s->d1s);
  s->d0 = d0; s->d1 = d1;
  s->h0 = (d0 < 1e-5f || d1 < 1e-5f) ? 1e-6f : 0.01f * d0 / d1;
}

__global__ void k_d2(const float* __restrict__ y, const u16* __restrict__ fb,
                     const u16* __restrict__ f1h, int n, Scal* s) {
  float a = 0.f;
  for (int i = blockIdx.x * blockDim.x + threadIdx.x; i < n; i += gridDim.x * blockDim.x) {
    float v = (bf2f(f1h[i]) - bf2f(fb[i])) / (1.f + fabsf(y[i]));
    a += v * v;
  }
  __shared__ float r0[256];
  int tid = threadIdx.x;
  r0[tid] = a;
  __syncthreads();
  for (int off = 128; off > 0; off >>= 1) {
    if (tid < off) r0[tid] += r0[tid + off];
    __syncthreads();
  }
  if (tid == 0) atomicAdd(&s->d2s, r0[0]);
}

__global__ void k_dt(Scal* s) {
  float d2 = sqrtf(s->d2s) / s->h0;          // 2-norm / h0
  float h1 = (s->d1 <= 1e-15f && d2 <= 1e-15f)
                 ? fmaxf(1e-6f, s->h0 * 1e-3f)
                 : powf(0.01f / fmaxf(s->d1, d2), 1.0f / 6.0f);  // 1/(order+1)
  s->dt = fminf(100.f * s->h0, h1);
  s->t = 0.f;
  s->last_t = 0.f;
}

__global__ void k_step_begin(Scal* s) {
  s->run_flag = (s->t < 1.0f) && (s->dt > 0.f);
  s->accept_flag = 0;
  s->errs = 0.f;
}

__global__ void k_step_end(Scal* s) {
  if (!s->run_flag) { s->accept_flag = 0; return; }
  float ratio = sqrtf(s->errs / (float)NTOT);
  int acc = (ratio <= 1.0f);
  s->accept_flag = acc;
  float dfactor = (ratio < 1.f) ? 1.f : 0.2f;
  float factor = fminf(10.f, fmaxf(0.9f * powf(ratio, -0.2f), dfactor));
  float ndt = (ratio == 0.f) ? s->dt * 10.f : s->dt * factor;
  if (ndt < 0.f) ndt = 0.f;
  if (acc) { s->dt_saved = s->dt; s->last_t = s->t; s->t = s->t + s->dt; }
  s->dt = ndt;
}

__global__ void k_flip(Scal* s) {
  if (s->accept_flag) s->cur ^= 1;
}

// interp_fit + polyval at r=(1-last_t)/(t-last_t); ym aliases out; f0/f1 bf16
__global__ void k_final(const float* YA, const float* YB,
    const u16* __restrict__ f0s, const u16* __restrict__ f1s,
    float* out, int n, const Scal* s) {
  int cur = s->cur;
  const float* y1s = cur ? YB : YA;
  const float* y0s = cur ? YA : YB;
  float dt = s->dt_saved;
  float r = (1.0f - s->last_t) / (s->t - s->last_t);
  for (int i = blockIdx.x * blockDim.x + threadIdx.x; i < n; i += gridDim.x * blockDim.x) {
    float y0 = y0s[i], y1 = y1s[i], ym = out[i];
    float f0 = bf2f(f0s[i]), f1 = bf2f(f1s[i]);
    float a = 2.f * dt * (f1 - f0) - 8.f * (y1 + y0) + 16.f * ym;
    float b = dt * (5.f * f0 - 3.f * f1) + 18.f * y0 + 14.f * y1 - 32.f * ym;
    float c = dt * (f1 - 4.f * f0) - 11.f * y0 - 5.f * y1 + 16.f * ym;
    float d = dt * f0;
    out[i] = (((a * r + b) * r + c) * r + d) * r + y0;
  }
}

__global__ void k_debug_ws(float* __restrict__ out, int n, float mb) {
  for (int i = blockIdx.x * blockDim.x + threadIdx.x; i < n; i += gridDim.x * blockDim.x)
    out[i] = mb;
}

// ================================  driver  ==================================
extern "C" void kernel_launch(void* const* d_in, const int* in_sizes, int n_in,
                              void* d_out, int out_size, void* d_ws, size_t ws_size,
                              hipStream_t stream) {
  const float* x  = (const float*)d_in[0];
  const float* W1 = (const float*)d_in[1];   // [2049, 2048]
  const float* b1 = (const float*)d_in[2];
  const float* W2 = (const float*)d_in[3];   // [2048, 2048]
  const float* b2 = (const float*)d_in[4];
  float* out = (float*)d_out;
  const float* w1row = W1 + (size_t)2048 * 2048;  // time row (kept fp32)

  const size_t SZW = (size_t)2048 * 2048 * 2;  // 8 MB
  const size_t SZH = (size_t)NTOT * 2;         // 16 MB
  const size_t SZF = (size_t)NTOT * 4;         // 32 MB
  // W1T,W2T + YSH,YSL,HH,HL + YA,YB + FB,KB2,KB3,KB4,KB6
  const size_t NEED = 1024 + 2 * SZW + 4 * SZH + 2 * SZF + 5 * SZH;  // 224 MB

  if (ws_size < NEED) {
    k_debug_ws<<<2048, 256, 0, stream>>>(out, NTOT, (float)(ws_size >> 20));
    return;
  }

  char* base = (char*)d_ws;
  Scal* s = (Scal*)base;
  size_t o = 1024;
  auto take = [&](size_t bytes) { void* p = base + o; o += bytes; return p; };

  u16* W1T = (u16*)take(SZW); u16* W2T = (u16*)take(SZW);
  u16* YSH = (u16*)take(SZH); u16* YSL = (u16*)take(SZH);
  u16* HH  = (u16*)take(SZH); u16* HL  = (u16*)take(SZH);
  float* YA = (float*)take(SZF); float* YB = (float*)take(SZF);
  u16* FB  = (u16*)take(SZH); u16* KB2 = (u16*)take(SZH);
  u16* KB3 = (u16*)take(SZH); u16* KB4 = (u16*)take(SZH);
  u16* KB6 = (u16*)take(SZH);
  float* Mout = out;   // M -> ymid -> final, all in d_out

  const dim3 GG(1024), GB(256);
  const dim3 EG(2048), EB(256);

  // gemm1: ys @ W1, tanh epilogue -> HH/HL
  #define G1(tmode, alpha, flag) \
    gemm_fused<100><<<GG, GB, 0, stream>>>(YSH, YSL, W1T, b1, w1row, \
        tmode, alpha, 0.f, 0.f, 0.f, 0.f, \
        YA, YB, FB, KB2, KB3, KB4, KB6, Mout, HH, HL, s, flag)
  // gemm2: h @ W2, stage-specific epilogue
  #define G2(st, b0, b1c, b2c, bv, flag) \
    gemm_fused<st><<<GG, GB, 0, stream>>>(HH, HL, W2T, b2, nullptr, \
        0, 0.f, b0, b1c, b2c, bv, \
        YA, YB, FB, KB2, KB3, KB4, KB6, Mout, YSH, YSL, s, flag)

  // ---- setup ----
  transpose_hi<<<dim3(64, 64), dim3(32, 8), 0, stream>>>(W1, W1T, 2048, 2048);
  transpose_hi<<<dim3(64, 64), dim3(32, 8), 0, stream>>>(W2, W2T, 2048, 2048);
  k_init_scal<<<1, 1, 0, stream>>>(s);
  k_init_y<<<EG, EB, 0, stream>>>(x, YA, YSH, YSL, NTOT);

  // ---- Hairer initial step size ----
  G1(0, 0.f, 0); G2(10, 0.f, 0.f, 0.f, 0.f, 0);        // f0 = f(y0, 0) -> FB
  k_d01<<<1024, 256, 0, stream>>>(YA, FB, NTOT, s);
  k_h0<<<1, 1, 0, stream>>>(s);
  k_probe_ys<<<EG, EB, 0, stream>>>(YA, FB, YSH, YSL, NTOT, s);
  G1(1, 0.f, 0); G2(11, 0.f, 0.f, 0.f, 0.f, 0);        // f(y0+h0*f0, h0) -> KB4
  k_d2<<<1024, 256, 0, stream>>>(YA, FB, KB4, NTOT, s);
  k_dt<<<1, 1, 0, stream>>>(s);
  k_prep<<<EG, EB, 0, stream>>>(YA, YB, FB, KB3, KB4, Mout, YSH, YSL, NTOT / 4, s, 1);

  // ---- adaptive Dopri5 trials (unrolled, device-predicated) ----
  for (int st = 0; st < MAX_STEPS; ++st) {
    k_step_begin<<<1, 1, 0, stream>>>(s);
    // k2
    G1(0, 0.2f, 1);
    G2(0, (float)(3.0/40.0), 0.f, 0.f, (float)(9.0/40.0), 1);
    // k3
    G1(0, 0.3f, 1);
    G2(1, (float)(44.0/45.0), (float)(-56.0/15.0), 0.f, (float)(32.0/9.0), 1);
    // k4
    G1(0, 0.8f, 1);
    G2(2, (float)(19372.0/6561.0), (float)(-25360.0/2187.0),
       (float)(64448.0/6561.0), (float)(-212.0/729.0), 1);
    // k5 (hardcoded B5x; k5 overwrites k2 plane)
    G1(0, (float)(8.0/9.0), 1);
    G2(3, 0.f, 0.f, 0.f, 0.f, 1);
    // k6 (NY + k6 stored bf16)
    G1(0, 1.f, 1);
    G2(4, 0.f, 0.f, 0.f, 0.f, 1);
    // k7 (E/M recomputed from bf16 k's, fused error reduction)
    G1(0, 1.f, 1);
    G2(5, 0.f, 0.f, 0.f, 0.f, 1);

    k_step_end<<<1, 1, 0, stream>>>(s);
    k_prep<<<EG, EB, 0, stream>>>(YA, YB, FB, KB3, KB4, Mout, YSH, YSL, NTOT / 4, s, 0);
    k_flip<<<1, 1, 0, stream>>>(s);
  }

  // ---- interpolate to t=1 (ymid already in `out`; f0 in KB3, f1 in FB) ----
  k_final<<<EG, EB, 0, stream>>>(YA, YB, KB3, FB, out, NTOT, s);

  #undef G1
  #undef G2
}

// Round 9
// 2558.245 us; speedup vs baseline: 1.0615x; 1.0615x over previous
//
#include <hip/hip_runtime.h>

typedef unsigned short u16;
typedef __attribute__((ext_vector_type(8))) short short8;
typedef __attribute__((ext_vector_type(4))) float floatx4;
typedef __attribute__((ext_vector_type(4))) unsigned short ushortx4;

#define BD 4096
#define DD 2048
#define NTOT (BD*DD)
#define MAX_STEPS 3

// ---- Dopri5 tableau, exactly as jax.experimental.ode (f64 exprs -> f32) ----
#define CE0 ((float)(35.0/384.0 - 1951.0/21600.0))
#define CE2 ((float)(500.0/1113.0 - 22642.0/50085.0))
#define CE3 ((float)(125.0/192.0 - 451.0/720.0))
#define CE4 ((float)(-2187.0/6784.0 + 12231.0/42400.0))
#define CE5 ((float)(11.0/84.0 - 649.0/6300.0))
#define CE6 ((float)(-1.0/60.0))

#define CM0 ((float)(6025192743.0/30085553152.0/2.0))
#define CM2 ((float)(51252292925.0/65400821598.0/2.0))
#define CM3 ((float)(-2691868925.0/45128329728.0/2.0))
#define CM4 ((float)(187940372067.0/1594534317056.0/2.0))
#define CM5 ((float)(-1776094331.0/19743644256.0/2.0))
#define CM6 ((float)(11237099.0/235043384.0/2.0))

#define CS0 ((float)(35.0/384.0))
#define CS2 ((float)(500.0/1113.0))
#define CS3 ((float)(125.0/192.0))
#define CS4 ((float)(-2187.0/6784.0))
#define CS5 ((float)(11.0/84.0))

#define B50 ((float)(9017.0/3168.0))
#define B51 ((float)(-355.0/33.0))
#define B52 ((float)(46732.0/5247.0))
#define B53 ((float)(49.0/176.0))
#define B54 ((float)(-5103.0/18656.0))

struct Scal {
  float t, dt, last_t, h0, dt_saved;
  float d0s, d1s, d2s, errs;
  float d0, d1;
  int run_flag, accept_flag, cur;
};

__device__ __forceinline__ u16 f2bf(float x) {
  unsigned int u = __float_as_uint(x);
  u += 0x7FFFu + ((u >> 16) & 1u);     // RNE
  return (u16)(u >> 16);
}
__device__ __forceinline__ float bf2f(u16 h) {
  return __uint_as_float(((unsigned int)h) << 16);
}
__device__ __forceinline__ void splitw(float v, u16* oh, u16* ol, size_t idx) {
  u16 h = f2bf(v);
  oh[idx] = h;
  ol[idx] = f2bf(v - bf2f(h));
}
// 4-wide split: hi/lo bf16 of 4 consecutive elements, one 8B store each
__device__ __forceinline__ void splitw4(floatx4 v, u16* oh, u16* ol, size_t idx) {
  ushortx4 h, l;
  #pragma unroll
  for (int e = 0; e < 4; ++e) {
    u16 hh = f2bf(v[e]);
    h[e] = hh;
    l[e] = f2bf(v[e] - bf2f(hh));
  }
  *(ushortx4*)&oh[idx] = h;
  *(ushortx4*)&ol[idx] = l;
}
// bf16 plane helpers (8B coalesced per lane)
__device__ __forceinline__ floatx4 bf4(ushortx4 u) {
  floatx4 f;
  #pragma unroll
  for (int e = 0; e < 4; ++e) f[e] = bf2f(u[e]);
  return f;
}
__device__ __forceinline__ floatx4 load4bf(const u16* __restrict__ p, size_t idx) {
  return bf4(*(const ushortx4*)&p[idx]);
}
__device__ __forceinline__ void store4bf(u16* __restrict__ p, size_t idx, floatx4 v) {
  ushortx4 u;
  #pragma unroll
  for (int e = 0; e < 4; ++e) u[e] = f2bf(v[e]);
  *(ushortx4*)&p[idx] = u;
}

// async global->LDS DMA, 16 B per lane. LDS dest = uniform base + lane*16.
__device__ __forceinline__ void gload16(const u16* g, u16* l) {
  __builtin_amdgcn_global_load_lds(
      (const __attribute__((address_space(1))) void*)g,
      (__attribute__((address_space(3))) void*)l, 16, 0, 0);
}

// =================  weight transpose -> bf16 [N][K]  =================
__global__ void transpose_hi(const float* __restrict__ W, u16* __restrict__ th,
                             int K, int N) {
  __shared__ float tile[32][33];
  int k0 = blockIdx.x * 32, n0 = blockIdx.y * 32;
  int tx = threadIdx.x, ty = threadIdx.y;   // 32 x 8
  #pragma unroll
  for (int j = 0; j < 32; j += 8)
    tile[ty + j][tx] = W[(size_t)(k0 + ty + j) * N + n0 + tx];
  __syncthreads();
  #pragma unroll
  for (int j = 0; j < 32; j += 8) {
    int nn = ty + j, kk = tx;
    th[(size_t)(n0 + nn) * K + k0 + kk] = f2bf(tile[kk][nn]);
  }
}

// ==============  split-A bf16 MFMA GEMM, fused Dopri5 epilogues  ============
// R6 base (verified 2405us): 64x128, BK=64, grid 1024, 64KB dbuf LDS,
// counted-vmcnt pipeline, bf16 k-planes, coalesced LDS-roundtrip epilogue.
// R8 (6-stream reg prefetch + in-loop t==const branches) regressed 86->149us:
// ~96 prefetch VGPRs at VGPR_Count 128 -> scratch spill + broken loop codegen.
// R9: T14-lite.  Prefetch ONLY F (16 VGPR) + Yc (32 VGPR); peel t=0,1,2 so
// the steady loop (t>=3) is byte-identical to R6.  vmcnt by in-order
// retirement: peels wait 16/24/16 (PFX) or 8/8/8.  Empty "memory" asm pins
// issue order (prefetch can't hoist above stage()).  Same values read ->
// same trajectory, absmax 0.03125.
template <int STAGE>
__global__ __launch_bounds__(256, 2)
void gemm_fused(const u16* __restrict__ Ah, const u16* __restrict__ Al,
                const u16* __restrict__ Bt,
                const float* __restrict__ bias, const float* __restrict__ trow,
                int tmode, float alpha_c,
                float bb0, float bb1, float bb2, float bbv,
                float* __restrict__ YA, float* __restrict__ YB,
                u16* __restrict__ FB, u16* __restrict__ KB2,
                u16* __restrict__ KB3, u16* __restrict__ KB4,
                u16* __restrict__ KB6, float* __restrict__ Mout,
                u16* __restrict__ oh, u16* __restrict__ ol,
                Scal* __restrict__ s, int flag) {
  if (flag == 1 && !s->run_flag) return;

  __shared__ __attribute__((aligned(16))) u16 raw[2][16384];
  #define AH_OFF 0
  #define AL_OFF 4096
  #define B_OFF  8192

  const int tid = threadIdx.x;
  const int lane = tid & 63;
  const int wave = tid >> 6;

  const int lin = blockIdx.x;
  const int xcd = lin & 7;
  const int slot = lin >> 3;                 // 0..127
  const int bm = (xcd * 8 + (slot >> 4)) * 64;
  const int bn = (slot & 15) * 128;

  const int m_w = (wave >> 1) * 32;          // 2 M-waves x 2 N-waves
  const int n_w = (wave & 1) * 64;
  const int lr = lane & 15;

  const int cur = s->cur;
  const float* Yc = cur ? YB : YA;
  float* NY = cur ? YA : YB;
  const float dt = s->dt;
  float tj = 0.f;
  if (STAGE == 100) tj = (tmode == 0) ? (s->t + dt * alpha_c) : s->h0;

  const int lrow = lane >> 3;                       // 0..7
  const int lcol = (((lane & 7) ^ (lane >> 3)) << 3);
  const int ra = wave * 16;
  const int rb = wave * 32;
  const u16* gAh = Ah + (size_t)(bm + ra + lrow) * DD + lcol;
  const u16* gAl = Al + (size_t)(bm + ra + lrow) * DD + lcol;
  const u16* gB  = Bt + (size_t)(bn + rb + lrow) * DD + lcol;

  floatx4 acc[2][4];
  #pragma unroll
  for (int i = 0; i < 2; ++i)
    #pragma unroll
    for (int j = 0; j < 4; ++j)
      acc[i][j] = (floatx4){0.f, 0.f, 0.f, 0.f};

  auto stage = [&](int k0, int b) {
    #pragma unroll
    for (int t = 0; t < 2; ++t) {
      gload16(gAh + k0 + (size_t)(8 * t) * DD, &raw[b][AH_OFF + (ra + 8 * t) * 64]);
      gload16(gAl + k0 + (size_t)(8 * t) * DD, &raw[b][AL_OFF + (ra + 8 * t) * 64]);
    }
    #pragma unroll
    for (int t = 0; t < 4; ++t)
      gload16(gB + k0 + (size_t)(8 * t) * DD, &raw[b][B_OFF + (rb + 8 * t) * 64]);
  };

  auto compute = [&](int b) {
    #pragma unroll
    for (int kk = 0; kk < 2; ++kk) {   // k-slices +0 and +32
      const int cb = kk * 4 + (lane >> 4);          // global chunk 0..7
      short8 afh[2], afl[2], bfv[4];
      #pragma unroll
      for (int i = 0; i < 2; ++i) {
        int r = m_w + i * 16 + lr;
        int ar = r * 64 + ((cb ^ (lr & 7)) << 3);
        afh[i] = *(const short8*)&raw[b][AH_OFF + ar];
        afl[i] = *(const short8*)&raw[b][AL_OFF + ar];
      }
      #pragma unroll
      for (int j = 0; j < 4; ++j) {
        int r = n_w + j * 16 + lr;
        bfv[j] = *(const short8*)&raw[b][B_OFF + r * 64 + ((cb ^ (lr & 7)) << 3)];
      }
      #pragma unroll
      for (int i = 0; i < 2; ++i)
        #pragma unroll
        for (int j = 0; j < 4; ++j) {
          acc[i][j] = __builtin_amdgcn_mfma_f32_16x16x32_bf16(afh[i], bfv[j], acc[i][j], 0, 0, 0);
          acc[i][j] = __builtin_amdgcn_mfma_f32_16x16x32_bf16(afl[i], bfv[j], acc[i][j], 0, 0, 0);
        }
    }
  };

  auto pfidx = [&](int q) -> size_t {
    const int fidx = tid + 256 * q;
    return (size_t)(bm + (fidx >> 5)) * DD + bn + ((fidx & 31) << 2);
  };

  constexpr bool PFX = (STAGE >= 0 && STAGE <= 5);
  ushortx4 pF[8];
  floatx4 pY[8];

  stage(0, 0);
  stage(64, 1);
  asm volatile("s_waitcnt vmcnt(8)" ::: "memory");
  __builtin_amdgcn_s_barrier();

  const int NT = DD / 64;              // 32 K-tiles

  // ---- peeled t=0: issue pF after staging tile 2 ----
  compute(0);
  __builtin_amdgcn_s_barrier();
  stage(128, 0);
  if constexpr (PFX) {
    asm volatile("" ::: "memory");     // pin issue order: stage before pf
    #pragma unroll
    for (int q = 0; q < 8; ++q) pF[q] = *(const ushortx4*)&FB[pfidx(q)];
    asm volatile("s_waitcnt vmcnt(16)" ::: "memory");  // retire tile1
  } else {
    asm volatile("s_waitcnt vmcnt(8)" ::: "memory");
  }
  __builtin_amdgcn_s_barrier();

  // ---- peeled t=1: issue pY after staging tile 3 ----
  compute(1);
  __builtin_amdgcn_s_barrier();
  stage(192, 1);
  if constexpr (PFX) {
    asm volatile("" ::: "memory");
    #pragma unroll
    for (int q = 0; q < 8; ++q) pY[q] = *(const floatx4*)&Yc[pfidx(q)];
    asm volatile("s_waitcnt vmcnt(24)" ::: "memory");  // retire tile2
  } else {
    asm volatile("s_waitcnt vmcnt(8)" ::: "memory");
  }
  __builtin_amdgcn_s_barrier();

  // ---- peeled t=2 ----
  compute(0);
  __builtin_amdgcn_s_barrier();
  stage(256, 0);
  if constexpr (PFX) {
    asm volatile("s_waitcnt vmcnt(16)" ::: "memory");  // retire pF + tile3
  } else {
    asm volatile("s_waitcnt vmcnt(8)" ::: "memory");
  }
  __builtin_amdgcn_s_barrier();

  // ---- steady loop (identical to R6) ----
  int bufc = 1;
  for (int t = 3; t < NT; ++t) {
    compute(bufc);
    if (t < NT - 1) {
      __builtin_amdgcn_s_barrier();
      if (t < NT - 2) {
        stage((t + 2) * 64, bufc);
        asm volatile("s_waitcnt vmcnt(8)" ::: "memory");
      } else {
        asm volatile("s_waitcnt vmcnt(0)" ::: "memory");
      }
      __builtin_amdgcn_s_barrier();
      bufc ^= 1;
    }
  }

  // ---- epilogue: acc -> padded LDS f32 tile -> vectorized global I/O ----
  __syncthreads();
  float* ep = (float*)&raw[0][0];      // 64 x 132 f32 = 33792 B
  const int oq = (lane >> 4) * 4;
  const int oc = lane & 15;
  #pragma unroll
  for (int i = 0; i < 2; ++i)
    #pragma unroll
    for (int j = 0; j < 4; ++j)
      #pragma unroll
      for (int r = 0; r < 4; ++r)
        ep[(m_w + i * 16 + oq + r) * 132 + (n_w + j * 16 + oc)] = acc[i][j][r];
  __syncthreads();

  float err_acc = 0.f;
  #pragma unroll
  for (int q = 0; q < 8; ++q) {
    const int fidx = tid + 256 * q;
    const int rl = fidx >> 5;                 // local row 0..63
    const int cl = (fidx & 31) << 2;          // local col, % 4 == 0
    const int n = bn + cl;
    const size_t idx = (size_t)(bm + rl) * DD + n;
    floatx4 v = *(const floatx4*)&ep[rl * 132 + cl];
    {
      floatx4 b4 = *(const floatx4*)&bias[n];
      #pragma unroll
      for (int e = 0; e < 4; ++e) v[e] = v[e] + b4[e];
    }
    if constexpr (STAGE == 100) {
      floatx4 t4 = *(const floatx4*)&trow[n];
      floatx4 h4;
      #pragma unroll
      for (int e = 0; e < 4; ++e) h4[e] = tanhf(v[e] + tj * t4[e]);
      splitw4(h4, oh, ol, idx);
    } else if constexpr (STAGE == 0) {           // k2
      floatx4 fv = bf4(pF[q]);
      floatx4 yv = pY[q];
      store4bf(KB2, idx, v);
      floatx4 ys;
      #pragma unroll
      for (int e = 0; e < 4; ++e)
        ys[e] = yv[e] + dt * (bb0 * fv[e] + bbv * v[e]);
      splitw4(ys, oh, ol, idx);
    } else if constexpr (STAGE == 1) {           // k3
      floatx4 fv = bf4(pF[q]);
      floatx4 yv = pY[q];
      floatx4 k2 = load4bf(KB2, idx);
      store4bf(KB3, idx, v);
      floatx4 ys;
      #pragma unroll
      for (int e = 0; e < 4; ++e)
        ys[e] = yv[e] + dt * (bb0 * fv[e] + bb1 * k2[e] + bbv * v[e]);
      splitw4(ys, oh, ol, idx);
    } else if constexpr (STAGE == 2) {           // k4
      floatx4 fv = bf4(pF[q]);
      floatx4 yv = pY[q];
      floatx4 k2 = load4bf(KB2, idx);
      floatx4 k3 = load4bf(KB3, idx);
      store4bf(KB4, idx, v);
      floatx4 ys;
      #pragma unroll
      for (int e = 0; e < 4; ++e)
        ys[e] = yv[e] + dt * (bb0 * fv[e] + bb1 * k2[e] + bb2 * k3[e] + bbv * v[e]);
      splitw4(ys, oh, ol, idx);
    } else if constexpr (STAGE == 3) {           // k5: overwrite k2 plane
      floatx4 fv = bf4(pF[q]);
      floatx4 yv = pY[q];
      floatx4 k2 = load4bf(KB2, idx);
      floatx4 k3 = load4bf(KB3, idx);
      floatx4 k4 = load4bf(KB4, idx);
      store4bf(KB2, idx, v);                     // k5 (k2 dead)
      floatx4 ys;
      #pragma unroll
      for (int e = 0; e < 4; ++e)
        ys[e] = yv[e] + dt * (B50 * fv[e] + B51 * k2[e] + B52 * k3[e] + B53 * k4[e] + B54 * v[e]);
      splitw4(ys, oh, ol, idx);
    } else if constexpr (STAGE == 4) {           // k6: NY + store k6
      floatx4 fv = bf4(pF[q]);
      floatx4 yv = pY[q];
      floatx4 k3 = load4bf(KB3, idx);
      floatx4 k4 = load4bf(KB4, idx);
      floatx4 k5 = load4bf(KB2, idx);
      floatx4 ny;
      #pragma unroll
      for (int e = 0; e < 4; ++e)
        ny[e] = yv[e] + dt * (CS0 * fv[e] + CS2 * k3[e] + CS3 * k4[e] + CS4 * k5[e] + CS5 * v[e]);
      *(floatx4*)&NY[idx] = ny;
      store4bf(KB6, idx, v);
      splitw4(ny, oh, ol, idx);
    } else if constexpr (STAGE == 5) {           // k7 + E/M recompute + err
      floatx4 fv = bf4(pF[q]);
      floatx4 k3 = load4bf(KB3, idx);
      floatx4 k4 = load4bf(KB4, idx);
      floatx4 k5 = load4bf(KB2, idx);
      floatx4 k6 = load4bf(KB6, idx);
      floatx4 yv = pY[q];
      floatx4 nyv = *(const floatx4*)&NY[idx];
      floatx4 M4;
      #pragma unroll
      for (int e = 0; e < 4; ++e) {
        float Ef = CE0 * fv[e] + CE2 * k3[e] + CE3 * k4[e] + CE4 * k5[e] + CE5 * k6[e] + CE6 * v[e];
        M4[e] = CM0 * fv[e] + CM2 * k3[e] + CM3 * k4[e] + CM4 * k5[e] + CM5 * k6[e] + CM6 * v[e];
        float er = dt * Ef;
        float tol = 1.f + fmaxf(fabsf(yv[e]), fabsf(nyv[e]));
        float rr = er / tol;
        err_acc += rr * rr;
      }
      store4bf(KB4, idx, v);                     // k7 (k4 consumed above)
      *(floatx4*)&Mout[idx] = M4;
    } else if constexpr (STAGE == 10) {
      store4bf(FB, idx, v);
    } else {                                     // 11
      store4bf(KB4, idx, v);
    }
  }

  if constexpr (STAGE == 5) {
    __syncthreads();
    float* red = (float*)&raw[0][0];
    red[tid] = err_acc;
    __syncthreads();
    for (int off = 128; off > 0; off >>= 1) {
      if (tid < off) red[tid] += red[tid + off];
      __syncthreads();
    }
    if (tid == 0) atomicAdd(&s->errs, red[0]);
  }
  #undef AH_OFF
  #undef AL_OFF
  #undef B_OFF
}

// ============================  elementwise etc  =============================
__global__ void k_init_scal(Scal* s) {
  s->t = 0.f; s->dt = 0.f; s->last_t = 0.f; s->h0 = 0.f; s->dt_saved = 1.f;
  s->d0s = 0.f; s->d1s = 0.f; s->d2s = 0.f; s->errs = 0.f;
  s->d0 = 0.f; s->d1 = 0.f;
  s->run_flag = 0; s->accept_flag = 0; s->cur = 0;
}

__global__ void k_init_y(const float* __restrict__ x, float* __restrict__ y,
                         u16* __restrict__ ysh, u16* __restrict__ ysl, int n) {
  for (int i = blockIdx.x * blockDim.x + threadIdx.x; i < n; i += gridDim.x * blockDim.x) {
    float v = x[i];
    y[i] = v;
    splitw(v, ysh, ysl, i);
  }
}

__global__ void k_probe_ys(const float* __restrict__ y, const u16* __restrict__ fb,
                           u16* __restrict__ ysh, u16* __restrict__ ysl, int n,
                           const Scal* __restrict__ s) {
  float h0 = s->h0;
  for (int i = blockIdx.x * blockDim.x + threadIdx.x; i < n; i += gridDim.x * blockDim.x)
    splitw(y[i] + h0 * bf2f(fb[i]), ysh, ysl, i);
}

__global__ void k_prep(float* YA, float* YB, u16* __restrict__ FB,
                       u16* __restrict__ KB3, const u16* __restrict__ KB4,
                       float* __restrict__ Mout,
                       u16* __restrict__ ysh, u16* __restrict__ ysl, int n4,
                       const Scal* __restrict__ s, int mode) {
  if (mode == 0 && !s->run_flag) return;
  int acc = (mode == 0) ? s->accept_flag : 0;
  int cur = s->cur;
  const float* Yc = cur ? YB : YA;
  const float* Yn = cur ? YA : YB;
  float dtn = s->dt, dts = s->dt_saved;
  for (int i = blockIdx.x * blockDim.x + threadIdx.x; i < n4; i += gridDim.x * blockDim.x) {
    size_t idx = (size_t)i * 4;
    ushortx4 fold = *(const ushortx4*)&FB[idx];
    floatx4 ys;
    if (acc) {
      ushortx4 k7 = *(const ushortx4*)&KB4[idx];
      floatx4 yn4 = *(const floatx4*)&Yn[idx];
      floatx4 yc4 = *(const floatx4*)&Yc[idx];
      floatx4 m4 = *(const floatx4*)&Mout[idx];
      *(ushortx4*)&FB[idx] = k7;
      *(ushortx4*)&KB3[idx] = fold;
      floatx4 ym;
      #pragma unroll
      for (int e = 0; e < 4; ++e) ym[e] = yc4[e] + dts * m4[e];
      *(floatx4*)&Mout[idx] = ym;
      #pragma unroll
      for (int e = 0; e < 4; ++e) ys[e] = yn4[e] + dtn * 0.2f * bf2f(k7[e]);
    } else {
      floatx4 yc4 = *(const floatx4*)&Yc[idx];
      #pragma unroll
      for (int e = 0; e < 4; ++e) ys[e] = yc4[e] + dtn * 0.2f * bf2f(fold[e]);
    }
    splitw4(ys, ysh, ysl, idx);
  }
}

__global__ void k_d01(const float* __restrict__ y, const u16* __restrict__ fb,
                      int n, Scal* s) {
  float a0 = 0.f, a1 = 0.f;
  for (int i = blockIdx.x * blockDim.x + threadIdx.x; i < n; i += gridDim.x * blockDim.x) {
    float yv = y[i], fv = bf2f(fb[i]);
    float sc = 1.f + fabsf(yv);
    float t0 = yv / sc, t1 = fv / sc;
    a0 += t0 * t0;
    a1 += t1 * t1;
  }
  __shared__ float r0[256], r1[256];
  int tid = threadIdx.x;
  r0[tid] = a0; r1[tid] = a1;
  __syncthreads();
  for (int off = 128; off > 0; off >>= 1) {
    if (tid < off) { r0[tid] += r0[tid + off]; r1[tid] += r1[tid + off]; }
    __syncthreads();
  }
  if (tid == 0) { atomicAdd(&s->d0s, r0[0]); atomicAdd(&s->d1s, r1[0]); }
}

__global__ void k_h0(Scal* s) {
  float d0 = sqrtf(s->d0s);
  float d1 = sqrtf(s->d1s);
  s->d0 = d0; s->d1 = d1;
  s->h0 = (d0 < 1e-5f || d1 < 1e-5f) ? 1e-6f : 0.01f * d0 / d1;
}

__global__ void k_d2(const float* __restrict__ y, const u16* __restrict__ fb,
                     const u16* __restrict__ f1h, int n, Scal* s) {
  float a = 0.f;
  for (int i = blockIdx.x * blockDim.x + threadIdx.x; i < n; i += gridDim.x * blockDim.x) {
    float v = (bf2f(f1h[i]) - bf2f(fb[i])) / (1.f + fabsf(y[i]));
    a += v * v;
  }
  __shared__ float r0[256];
  int tid = threadIdx.x;
  r0[tid] = a;
  __syncthreads();
  for (int off = 128; off > 0; off >>= 1) {
    if (tid < off) r0[tid] += r0[tid + off];
    __syncthreads();
  }
  if (tid == 0) atomicAdd(&s->d2s, r0[0]);
}

__global__ void k_dt(Scal* s) {
  float d2 = sqrtf(s->d2s) / s->h0;
  float h1 = (s->d1 <= 1e-15f && d2 <= 1e-15f)
                 ? fmaxf(1e-6f, s->h0 * 1e-3f)
                 : powf(0.01f / fmaxf(s->d1, d2), 1.0f / 6.0f);
  s->dt = fminf(100.f * s->h0, h1);
  s->t = 0.f;
  s->last_t = 0.f;
}

__global__ void k_step_begin(Scal* s) {
  s->run_flag = (s->t < 1.0f) && (s->dt > 0.f);
  s->accept_flag = 0;
  s->errs = 0.f;
}

__global__ void k_step_end(Scal* s) {
  if (!s->run_flag) { s->accept_flag = 0; return; }
  float ratio = sqrtf(s->errs / (float)NTOT);
  int acc = (ratio <= 1.0f);
  s->accept_flag = acc;
  float dfactor = (ratio < 1.f) ? 1.f : 0.2f;
  float factor = fminf(10.f, fmaxf(0.9f * powf(ratio, -0.2f), dfactor));
  float ndt = (ratio == 0.f) ? s->dt * 10.f : s->dt * factor;
  if (ndt < 0.f) ndt = 0.f;
  if (acc) { s->dt_saved = s->dt; s->last_t = s->t; s->t = s->t + s->dt; }
  s->dt = ndt;
}

__global__ void k_flip(Scal* s) {
  if (s->accept_flag) s->cur ^= 1;
}

__global__ void k_final(const float* YA, const float* YB,
    const u16* __restrict__ f0s, const u16* __restrict__ f1s,
    float* out, int n, const Scal* s) {
  int cur = s->cur;
  const float* y1s = cur ? YB : YA;
  const float* y0s = cur ? YA : YB;
  float dt = s->dt_saved;
  float r = (1.0f - s->last_t) / (s->t - s->last_t);
  for (int i = blockIdx.x * blockDim.x + threadIdx.x; i < n; i += gridDim.x * blockDim.x) {
    float y0 = y0s[i], y1 = y1s[i], ym = out[i];
    float f0 = bf2f(f0s[i]), f1 = bf2f(f1s[i]);
    float a = 2.f * dt * (f1 - f0) - 8.f * (y1 + y0) + 16.f * ym;
    float b = dt * (5.f * f0 - 3.f * f1) + 18.f * y0 + 14.f * y1 - 32.f * ym;
    float c = dt * (f1 - 4.f * f0) - 11.f * y0 - 5.f * y1 + 16.f * ym;
    float d = dt * f0;
    out[i] = (((a * r + b) * r + c) * r + d) * r + y0;
  }
}

__global__ void k_debug_ws(float* __restrict__ out, int n, float mb) {
  for (int i = blockIdx.x * blockDim.x + threadIdx.x; i < n; i += gridDim.x * blockDim.x)
    out[i] = mb;
}

// ================================  driver  ==================================
extern "C" void kernel_launch(void* const* d_in, const int* in_sizes, int n_in,
                              void* d_out, int out_size, void* d_ws, size_t ws_size,
                              hipStream_t stream) {
  const float* x  = (const float*)d_in[0];
  const float* W1 = (const float*)d_in[1];   // [2049, 2048]
  const float* b1 = (const float*)d_in[2];
  const float* W2 = (const float*)d_in[3];   // [2048, 2048]
  const float* b2 = (const float*)d_in[4];
  float* out = (float*)d_out;
  const float* w1row = W1 + (size_t)2048 * 2048;  // time row (kept fp32)

  const size_t SZW = (size_t)2048 * 2048 * 2;  // 8 MB
  const size_t SZH = (size_t)NTOT * 2;         // 16 MB
  const size_t SZF = (size_t)NTOT * 4;         // 32 MB
  const size_t NEED = 1024 + 2 * SZW + 4 * SZH + 2 * SZF + 5 * SZH;  // 224 MB

  if (ws_size < NEED) {
    k_debug_ws<<<2048, 256, 0, stream>>>(out, NTOT, (float)(ws_size >> 20));
    return;
  }

  char* base = (char*)d_ws;
  Scal* s = (Scal*)base;
  size_t o = 1024;
  auto take = [&](size_t bytes) { void* p = base + o; o += bytes; return p; };

  u16* W1T = (u16*)take(SZW); u16* W2T = (u16*)take(SZW);
  u16* YSH = (u16*)take(SZH); u16* YSL = (u16*)take(SZH);
  u16* HH  = (u16*)take(SZH); u16* HL  = (u16*)take(SZH);
  float* YA = (float*)take(SZF); float* YB = (float*)take(SZF);
  u16* FB  = (u16*)take(SZH); u16* KB2 = (u16*)take(SZH);
  u16* KB3 = (u16*)take(SZH); u16* KB4 = (u16*)take(SZH);
  u16* KB6 = (u16*)take(SZH);
  float* Mout = out;

  const dim3 GG(1024), GB(256);
  const dim3 EG(2048), EB(256);

  #define G1(tmode, alpha, flag) \
    gemm_fused<100><<<GG, GB, 0, stream>>>(YSH, YSL, W1T, b1, w1row, \
        tmode, alpha, 0.f, 0.f, 0.f, 0.f, \
        YA, YB, FB, KB2, KB3, KB4, KB6, Mout, HH, HL, s, flag)
  #define G2(st, b0, b1c, b2c, bv, flag) \
    gemm_fused<st><<<GG, GB, 0, stream>>>(HH, HL, W2T, b2, nullptr, \
        0, 0.f, b0, b1c, b2c, bv, \
        YA, YB, FB, KB2, KB3, KB4, KB6, Mout, YSH, YSL, s, flag)

  transpose_hi<<<dim3(64, 64), dim3(32, 8), 0, stream>>>(W1, W1T, 2048, 2048);
  transpose_hi<<<dim3(64, 64), dim3(32, 8), 0, stream>>>(W2, W2T, 2048, 2048);
  k_init_scal<<<1, 1, 0, stream>>>(s);
  k_init_y<<<EG, EB, 0, stream>>>(x, YA, YSH, YSL, NTOT);

  G1(0, 0.f, 0); G2(10, 0.f, 0.f, 0.f, 0.f, 0);        // f0 -> FB
  k_d01<<<1024, 256, 0, stream>>>(YA, FB, NTOT, s);
  k_h0<<<1, 1, 0, stream>>>(s);
  k_probe_ys<<<EG, EB, 0, stream>>>(YA, FB, YSH, YSL, NTOT, s);
  G1(1, 0.f, 0); G2(11, 0.f, 0.f, 0.f, 0.f, 0);        // f(y0+h0*f0) -> KB4
  k_d2<<<1024, 256, 0, stream>>>(YA, FB, KB4, NTOT, s);
  k_dt<<<1, 1, 0, stream>>>(s);
  k_prep<<<EG, EB, 0, stream>>>(YA, YB, FB, KB3, KB4, Mout, YSH, YSL, NTOT / 4, s, 1);

  for (int st = 0; st < MAX_STEPS; ++st) {
    k_step_begin<<<1, 1, 0, stream>>>(s);
    G1(0, 0.2f, 1);
    G2(0, (float)(3.0/40.0), 0.f, 0.f, (float)(9.0/40.0), 1);
    G1(0, 0.3f, 1);
    G2(1, (float)(44.0/45.0), (float)(-56.0/15.0), 0.f, (float)(32.0/9.0), 1);
    G1(0, 0.8f, 1);
    G2(2, (float)(19372.0/6561.0), (float)(-25360.0/2187.0),
       (float)(64448.0/6561.0), (float)(-212.0/729.0), 1);
    G1(0, (float)(8.0/9.0), 1);
    G2(3, 0.f, 0.f, 0.f, 0.f, 1);
    G1(0, 1.f, 1);
    G2(4, 0.f, 0.f, 0.f, 0.f, 1);
    G1(0, 1.f, 1);
    G2(5, 0.f, 0.f, 0.f, 0.f, 1);

    k_step_end<<<1, 1, 0, stream>>>(s);
    k_prep<<<EG, EB, 0, stream>>>(YA, YB, FB, KB3, KB4, Mout, YSH, YSL, NTOT / 4, s, 0);
    k_flip<<<1, 1, 0, stream>>>(s);
  }

  k_final<<<EG, EB, 0, stream>>>(YA, YB, KB3, FB, out, NTOT, s);

  #undef G1
  #undef G2
}

// Round 10
// 2361.084 us; speedup vs baseline: 1.1502x; 1.0835x over previous
//
#include <hip/hip_runtime.h>

typedef unsigned short u16;
typedef __attribute__((ext_vector_type(8))) short short8;
typedef __attribute__((ext_vector_type(4))) float floatx4;
typedef __attribute__((ext_vector_type(4))) unsigned short ushortx4;

#define BD 4096
#define DD 2048
#define NTOT (BD*DD)
#define MAX_STEPS 3

// ---- Dopri5 tableau, exactly as jax.experimental.ode (f64 exprs -> f32) ----
#define CE0 ((float)(35.0/384.0 - 1951.0/21600.0))
#define CE2 ((float)(500.0/1113.0 - 22642.0/50085.0))
#define CE3 ((float)(125.0/192.0 - 451.0/720.0))
#define CE4 ((float)(-2187.0/6784.0 + 12231.0/42400.0))
#define CE5 ((float)(11.0/84.0 - 649.0/6300.0))
#define CE6 ((float)(-1.0/60.0))

#define CM0 ((float)(6025192743.0/30085553152.0/2.0))
#define CM2 ((float)(51252292925.0/65400821598.0/2.0))
#define CM3 ((float)(-2691868925.0/45128329728.0/2.0))
#define CM4 ((float)(187940372067.0/1594534317056.0/2.0))
#define CM5 ((float)(-1776094331.0/19743644256.0/2.0))
#define CM6 ((float)(11237099.0/235043384.0/2.0))

#define CS0 ((float)(35.0/384.0))
#define CS2 ((float)(500.0/1113.0))
#define CS3 ((float)(125.0/192.0))
#define CS4 ((float)(-2187.0/6784.0))
#define CS5 ((float)(11.0/84.0))

#define B50 ((float)(9017.0/3168.0))
#define B51 ((float)(-355.0/33.0))
#define B52 ((float)(46732.0/5247.0))
#define B53 ((float)(49.0/176.0))
#define B54 ((float)(-5103.0/18656.0))

struct Scal {
  float t, dt, last_t, h0, dt_saved;
  float d0s, d1s, d2s, errs;
  float d0, d1;
  int run_flag, accept_flag, cur;
};

__device__ __forceinline__ u16 f2bf(float x) {
  unsigned int u = __float_as_uint(x);
  u += 0x7FFFu + ((u >> 16) & 1u);     // RNE
  return (u16)(u >> 16);
}
__device__ __forceinline__ float bf2f(u16 h) {
  return __uint_as_float(((unsigned int)h) << 16);
}
__device__ __forceinline__ void splitw(float v, u16* oh, u16* ol, size_t idx) {
  u16 h = f2bf(v);
  oh[idx] = h;
  ol[idx] = f2bf(v - bf2f(h));
}
// 4-wide split: hi/lo bf16 of 4 consecutive elements, one 8B store each
__device__ __forceinline__ void splitw4(floatx4 v, u16* oh, u16* ol, size_t idx) {
  ushortx4 h, l;
  #pragma unroll
  for (int e = 0; e < 4; ++e) {
    u16 hh = f2bf(v[e]);
    h[e] = hh;
    l[e] = f2bf(v[e] - bf2f(hh));
  }
  *(ushortx4*)&oh[idx] = h;
  *(ushortx4*)&ol[idx] = l;
}
// bf16 plane helpers (8B coalesced per lane)
__device__ __forceinline__ floatx4 load4bf(const u16* __restrict__ p, size_t idx) {
  ushortx4 u = *(const ushortx4*)&p[idx];
  floatx4 f;
  #pragma unroll
  for (int e = 0; e < 4; ++e) f[e] = bf2f(u[e]);
  return f;
}
__device__ __forceinline__ void store4bf(u16* __restrict__ p, size_t idx, floatx4 v) {
  ushortx4 u;
  #pragma unroll
  for (int e = 0; e < 4; ++e) u[e] = f2bf(v[e]);
  *(ushortx4*)&p[idx] = u;
}

// async global->LDS DMA, 16 B per lane. LDS dest = uniform base + lane*16.
__device__ __forceinline__ void gload16(const u16* g, u16* l) {
  __builtin_amdgcn_global_load_lds(
      (const __attribute__((address_space(1))) void*)g,
      (__attribute__((address_space(3))) void*)l, 16, 0, 0);
}

// =================  weight transpose -> bf16 [N][K]  =================
__global__ void transpose_hi(const float* __restrict__ W, u16* __restrict__ th,
                             int K, int N) {
  __shared__ float tile[32][33];
  int k0 = blockIdx.x * 32, n0 = blockIdx.y * 32;
  int tx = threadIdx.x, ty = threadIdx.y;   // 32 x 8
  #pragma unroll
  for (int j = 0; j < 32; j += 8)
    tile[ty + j][tx] = W[(size_t)(k0 + ty + j) * N + n0 + tx];
  __syncthreads();
  #pragma unroll
  for (int j = 0; j < 32; j += 8) {
    int nn = ty + j, kk = tx;
    th[(size_t)(n0 + nn) * K + k0 + kk] = f2bf(tile[kk][nn]);
  }
}

// ==============  split-A bf16 MFMA GEMM, fused Dopri5 epilogues  ============
// SESSION-BEST configuration (verified 2405us, absmax 0.03125, hot dispatch
// 86us, MfmaUtil 33%).  64x128 tile, BK=64, grid 1024, LDS 64KB dbuf,
// counted-vmcnt pipeline (vmcnt(8), never 0 mid-loop), bf16 RK slope planes
// (FB, KB2=k2/k5, KB3=k3, KB4=k4/k7, KB6=k6), f32 Y/NY/M, coalesced
// LDS-roundtrip epilogue (all global I/O float4/ushortx4).
// Session evidence (9 rounds): occupancy alone null (R1); 2-phase pipeline
// +12% (R2); counted-vmcnt null on top (R3); coalesced epilogue +15% (R4);
// BK=32/4-blocks -8% via L2 thrash (R5); bf16 k-planes +8% (R6, this);
// f16 operands FAIL absmax (R7 - split-A precision is load-bearing);
// epilogue reg-prefetch -30%/-23% (R8 spill / R9 AGPR-shuffle).  Residual
// gap to the ~55us overlapped floor is the serial {K-loop | epilogue}
// structure + barrier drain; proven escapes are 256sq/8-phase-class
// rewrites whose ingredients each regressed here.
template <int STAGE>
__global__ __launch_bounds__(256, 2)
void gemm_fused(const u16* __restrict__ Ah, const u16* __restrict__ Al,
                const u16* __restrict__ Bt,
                const float* __restrict__ bias, const float* __restrict__ trow,
                int tmode, float alpha_c,
                float bb0, float bb1, float bb2, float bbv,
                float* __restrict__ YA, float* __restrict__ YB,
                u16* __restrict__ FB, u16* __restrict__ KB2,
                u16* __restrict__ KB3, u16* __restrict__ KB4,
                u16* __restrict__ KB6, float* __restrict__ Mout,
                u16* __restrict__ oh, u16* __restrict__ ol,
                Scal* __restrict__ s, int flag) {
  if (flag == 1 && !s->run_flag) return;

  // one contiguous 64KB block: per buffer [Ah 4096 | Al 4096 | B 8192] u16
  __shared__ __attribute__((aligned(16))) u16 raw[2][16384];
  #define AH_OFF 0
  #define AL_OFF 4096
  #define B_OFF  8192

  const int tid = threadIdx.x;
  const int lane = tid & 63;
  const int wave = tid >> 6;

  // XCD-aware swizzle: each XCD (lin&7) owns 8 bm-strips x all 16 bn.
  const int lin = blockIdx.x;
  const int xcd = lin & 7;
  const int slot = lin >> 3;                 // 0..127
  const int bm = (xcd * 8 + (slot >> 4)) * 64;
  const int bn = (slot & 15) * 128;

  const int m_w = (wave >> 1) * 32;          // 2 M-waves x 2 N-waves
  const int n_w = (wave & 1) * 64;
  const int lr = lane & 15;

  // DMA: one instr = 8 rows x 128 B.  Lane l -> row base+(l>>3), global
  // chunk g=(l&7)^(l>>3); LDS dest base+l*16 -> swizzled pos p = l&7.
  const int lrow = lane >> 3;                       // 0..7
  const int lcol = (((lane & 7) ^ (lane >> 3)) << 3);
  const int ra = wave * 16;
  const int rb = wave * 32;
  const u16* gAh = Ah + (size_t)(bm + ra + lrow) * DD + lcol;
  const u16* gAl = Al + (size_t)(bm + ra + lrow) * DD + lcol;
  const u16* gB  = Bt + (size_t)(bn + rb + lrow) * DD + lcol;

  floatx4 acc[2][4];
  #pragma unroll
  for (int i = 0; i < 2; ++i)
    #pragma unroll
    for (int j = 0; j < 4; ++j)
      acc[i][j] = (floatx4){0.f, 0.f, 0.f, 0.f};

  // stage K-tile at k0 into buffer b (8 global_load_lds per wave)
  auto stage = [&](int k0, int b) {
    #pragma unroll
    for (int t = 0; t < 2; ++t) {
      gload16(gAh + k0 + (size_t)(8 * t) * DD, &raw[b][AH_OFF + (ra + 8 * t) * 64]);
      gload16(gAl + k0 + (size_t)(8 * t) * DD, &raw[b][AL_OFF + (ra + 8 * t) * 64]);
    }
    #pragma unroll
    for (int t = 0; t < 4; ++t)
      gload16(gB + k0 + (size_t)(8 * t) * DD, &raw[b][B_OFF + (rb + 8 * t) * 64]);
  };

  // prologue: tiles 0 and 1 in flight; wait only for tile 0 (vmcnt(8))
  stage(0, 0);
  stage(64, 1);
  asm volatile("s_waitcnt vmcnt(8)" ::: "memory");
  __builtin_amdgcn_s_barrier();

  const int NT = DD / 64;              // 32 K-tiles
  int bufc = 0;
  for (int t = 0; t < NT; ++t) {
    #pragma unroll
    for (int kk = 0; kk < 2; ++kk) {   // k-slices +0 and +32
      const int cb = kk * 4 + (lane >> 4);          // global chunk 0..7
      short8 afh[2], afl[2], bfv[4];
      #pragma unroll
      for (int i = 0; i < 2; ++i) {
        int r = m_w + i * 16 + lr;
        int ar = r * 64 + ((cb ^ (lr & 7)) << 3);
        afh[i] = *(const short8*)&raw[bufc][AH_OFF + ar];
        afl[i] = *(const short8*)&raw[bufc][AL_OFF + ar];
      }
      #pragma unroll
      for (int j = 0; j < 4; ++j) {
        int r = n_w + j * 16 + lr;
        bfv[j] = *(const short8*)&raw[bufc][B_OFF + r * 64 + ((cb ^ (lr & 7)) << 3)];
      }
      #pragma unroll
      for (int i = 0; i < 2; ++i)
        #pragma unroll
        for (int j = 0; j < 4; ++j) {
          acc[i][j] = __builtin_amdgcn_mfma_f32_16x16x32_bf16(afh[i], bfv[j], acc[i][j], 0, 0, 0);
          acc[i][j] = __builtin_amdgcn_mfma_f32_16x16x32_bf16(afl[i], bfv[j], acc[i][j], 0, 0, 0);
        }
    }

    if (t < NT - 1) {
      // all waves' ds_reads of bufc complete (lgkmcnt-waited before MFMAs)
      __builtin_amdgcn_s_barrier();
      if (t < NT - 2) {
        stage((t + 2) * 64, bufc);     // overwrite consumed buffer
        // wait for tile t+1's 8 loads; tile t+2's 8 stay in flight
        asm volatile("s_waitcnt vmcnt(8)" ::: "memory");
      } else {
        asm volatile("s_waitcnt vmcnt(0)" ::: "memory");
      }
      __builtin_amdgcn_s_barrier();    // tile t+1 visible to all waves
      bufc ^= 1;
    }
  }

  const int cur = s->cur;
  const float* Yc = cur ? YB : YA;
  float* NY = cur ? YA : YB;
  const float dt = s->dt;
  float tj = 0.f;
  if (STAGE == 100) tj = (tmode == 0) ? (s->t + dt * alpha_c) : s->h0;

  // ---- epilogue: acc -> padded LDS f32 tile -> vectorized global I/O ----
  __syncthreads();                     // staging LDS dead; vmcnt drained
  float* ep = (float*)&raw[0][0];      // 64 x 132 f32 = 33792 B (< 64 KB)
  const int oq = (lane >> 4) * 4;
  const int oc = lane & 15;
  #pragma unroll
  for (int i = 0; i < 2; ++i)
    #pragma unroll
    for (int j = 0; j < 4; ++j)
      #pragma unroll
      for (int r = 0; r < 4; ++r)
        ep[(m_w + i * 16 + oq + r) * 132 + (n_w + j * 16 + oc)] = acc[i][j][r];
  __syncthreads();

  float err_acc = 0.f;
  #pragma unroll
  for (int q = 0; q < 8; ++q) {
    const int fidx = tid + 256 * q;
    const int rl = fidx >> 5;                 // local row 0..63
    const int cl = (fidx & 31) << 2;          // local col, % 4 == 0
    const int n = bn + cl;
    const size_t idx = (size_t)(bm + rl) * DD + n;
    floatx4 v = *(const floatx4*)&ep[rl * 132 + cl];
    {
      floatx4 b4 = *(const floatx4*)&bias[n];
      #pragma unroll
      for (int e = 0; e < 4; ++e) v[e] = v[e] + b4[e];
    }
    if constexpr (STAGE == 100) {
      floatx4 t4 = *(const floatx4*)&trow[n];
      floatx4 h4;
      #pragma unroll
      for (int e = 0; e < 4; ++e) h4[e] = tanhf(v[e] + tj * t4[e]);
      splitw4(h4, oh, ol, idx);
    } else if constexpr (STAGE == 0) {           // k2
      floatx4 fv = load4bf(FB, idx);
      floatx4 yv = *(const floatx4*)&Yc[idx];
      store4bf(KB2, idx, v);
      floatx4 ys;
      #pragma unroll
      for (int e = 0; e < 4; ++e)
        ys[e] = yv[e] + dt * (bb0 * fv[e] + bbv * v[e]);
      splitw4(ys, oh, ol, idx);
    } else if constexpr (STAGE == 1) {           // k3
      floatx4 fv = load4bf(FB, idx);
      floatx4 yv = *(const floatx4*)&Yc[idx];
      floatx4 k2 = load4bf(KB2, idx);
      store4bf(KB3, idx, v);
      floatx4 ys;
      #pragma unroll
      for (int e = 0; e < 4; ++e)
        ys[e] = yv[e] + dt * (bb0 * fv[e] + bb1 * k2[e] + bbv * v[e]);
      splitw4(ys, oh, ol, idx);
    } else if constexpr (STAGE == 2) {           // k4
      floatx4 fv = load4bf(FB, idx);
      floatx4 yv = *(const floatx4*)&Yc[idx];
      floatx4 k2 = load4bf(KB2, idx);
      floatx4 k3 = load4bf(KB3, idx);
      store4bf(KB4, idx, v);
      floatx4 ys;
      #pragma unroll
      for (int e = 0; e < 4; ++e)
        ys[e] = yv[e] + dt * (bb0 * fv[e] + bb1 * k2[e] + bb2 * k3[e] + bbv * v[e]);
      splitw4(ys, oh, ol, idx);
    } else if constexpr (STAGE == 3) {           // k5: overwrite k2 plane
      floatx4 fv = load4bf(FB, idx);
      floatx4 yv = *(const floatx4*)&Yc[idx];
      floatx4 k2 = load4bf(KB2, idx);
      floatx4 k3 = load4bf(KB3, idx);
      floatx4 k4 = load4bf(KB4, idx);
      store4bf(KB2, idx, v);                     // k5 (k2 dead)
      floatx4 ys;
      #pragma unroll
      for (int e = 0; e < 4; ++e)
        ys[e] = yv[e] + dt * (B50 * fv[e] + B51 * k2[e] + B52 * k3[e] + B53 * k4[e] + B54 * v[e]);
      splitw4(ys, oh, ol, idx);
    } else if constexpr (STAGE == 4) {           // k6: NY + store k6
      floatx4 fv = load4bf(FB, idx);
      floatx4 yv = *(const floatx4*)&Yc[idx];
      floatx4 k3 = load4bf(KB3, idx);
      floatx4 k4 = load4bf(KB4, idx);
      floatx4 k5 = load4bf(KB2, idx);
      floatx4 ny;
      #pragma unroll
      for (int e = 0; e < 4; ++e)
        ny[e] = yv[e] + dt * (CS0 * fv[e] + CS2 * k3[e] + CS3 * k4[e] + CS4 * k5[e] + CS5 * v[e]);
      *(floatx4*)&NY[idx] = ny;
      store4bf(KB6, idx, v);
      splitw4(ny, oh, ol, idx);
    } else if constexpr (STAGE == 5) {           // k7 + E/M recompute + err
      floatx4 fv = load4bf(FB, idx);
      floatx4 k3 = load4bf(KB3, idx);
      floatx4 k4 = load4bf(KB4, idx);
      floatx4 k5 = load4bf(KB2, idx);
      floatx4 k6 = load4bf(KB6, idx);
      floatx4 yv = *(const floatx4*)&Yc[idx];
      floatx4 nyv = *(const floatx4*)&NY[idx];
      floatx4 M4;
      #pragma unroll
      for (int e = 0; e < 4; ++e) {
        float Ef = CE0 * fv[e] + CE2 * k3[e] + CE3 * k4[e] + CE4 * k5[e] + CE5 * k6[e] + CE6 * v[e];
        M4[e] = CM0 * fv[e] + CM2 * k3[e] + CM3 * k4[e] + CM4 * k5[e] + CM5 * k6[e] + CM6 * v[e];
        float er = dt * Ef;
        float tol = 1.f + fmaxf(fabsf(yv[e]), fabsf(nyv[e]));
        float rr = er / tol;
        err_acc += rr * rr;
      }
      store4bf(KB4, idx, v);                     // k7 (k4 consumed above)
      *(floatx4*)&Mout[idx] = M4;
    } else if constexpr (STAGE == 10) {
      store4bf(FB, idx, v);
    } else {                                     // 11
      store4bf(KB4, idx, v);
    }
  }

  if constexpr (STAGE == 5) {
    __syncthreads();                   // ep reads done
    float* red = (float*)&raw[0][0];
    red[tid] = err_acc;
    __syncthreads();
    for (int off = 128; off > 0; off >>= 1) {
      if (tid < off) red[tid] += red[tid + off];
      __syncthreads();
    }
    if (tid == 0) atomicAdd(&s->errs, red[0]);
  }
  #undef AH_OFF
  #undef AL_OFF
  #undef B_OFF
}

// ============================  elementwise etc  =============================
__global__ void k_init_scal(Scal* s) {
  s->t = 0.f; s->dt = 0.f; s->last_t = 0.f; s->h0 = 0.f; s->dt_saved = 1.f;
  s->d0s = 0.f; s->d1s = 0.f; s->d2s = 0.f; s->errs = 0.f;
  s->d0 = 0.f; s->d1 = 0.f;
  s->run_flag = 0; s->accept_flag = 0; s->cur = 0;
}

__global__ void k_init_y(const float* __restrict__ x, float* __restrict__ y,
                         u16* __restrict__ ysh, u16* __restrict__ ysl, int n) {
  for (int i = blockIdx.x * blockDim.x + threadIdx.x; i < n; i += gridDim.x * blockDim.x) {
    float v = x[i];
    y[i] = v;
    splitw(v, ysh, ysl, i);
  }
}

// ys = y0 + h0 * f0 (heuristic probe input); f0 bf16
__global__ void k_probe_ys(const float* __restrict__ y, const u16* __restrict__ fb,
                           u16* __restrict__ ysh, u16* __restrict__ ysl, int n,
                           const Scal* __restrict__ s) {
  float h0 = s->h0;
  for (int i = blockIdx.x * blockDim.x + threadIdx.x; i < n; i += gridDim.x * blockDim.x)
    splitw(y[i] + h0 * bf2f(fb[i]), ysh, ysl, i);
}

// End-of-trial bookkeeping + next-trial first-stage input (4-wide).
// accept: KB3 = FB_old (f0save); FB = k7(KB4); Mout = Yc + dts*Mout (ymid);
//         y' = NY.  reject: y' = Yc, FB unchanged.
// Then ys2 = split(y' + dt_new*0.2*f').
__global__ void k_prep(float* YA, float* YB, u16* __restrict__ FB,
                       u16* __restrict__ KB3, const u16* __restrict__ KB4,
                       float* __restrict__ Mout,
                       u16* __restrict__ ysh, u16* __restrict__ ysl, int n4,
                       const Scal* __restrict__ s, int mode) {
  if (mode == 0 && !s->run_flag) return;
  int acc = (mode == 0) ? s->accept_flag : 0;
  int cur = s->cur;
  const float* Yc = cur ? YB : YA;
  const float* Yn = cur ? YA : YB;
  float dtn = s->dt, dts = s->dt_saved;
  for (int i = blockIdx.x * blockDim.x + threadIdx.x; i < n4; i += gridDim.x * blockDim.x) {
    size_t idx = (size_t)i * 4;
    ushortx4 fold = *(const ushortx4*)&FB[idx];
    floatx4 ys;
    if (acc) {
      ushortx4 k7 = *(const ushortx4*)&KB4[idx];
      floatx4 yn4 = *(const floatx4*)&Yn[idx];
      floatx4 yc4 = *(const floatx4*)&Yc[idx];
      floatx4 m4 = *(const floatx4*)&Mout[idx];
      *(ushortx4*)&FB[idx] = k7;
      *(ushortx4*)&KB3[idx] = fold;
      floatx4 ym;
      #pragma unroll
      for (int e = 0; e < 4; ++e) ym[e] = yc4[e] + dts * m4[e];
      *(floatx4*)&Mout[idx] = ym;
      #pragma unroll
      for (int e = 0; e < 4; ++e) ys[e] = yn4[e] + dtn * 0.2f * bf2f(k7[e]);
    } else {
      floatx4 yc4 = *(const floatx4*)&Yc[idx];
      #pragma unroll
      for (int e = 0; e < 4; ++e) ys[e] = yc4[e] + dtn * 0.2f * bf2f(fold[e]);
    }
    splitw4(ys, ysh, ysl, idx);
  }
}

__global__ void k_d01(const float* __restrict__ y, const u16* __restrict__ fb,
                      int n, Scal* s) {
  float a0 = 0.f, a1 = 0.f;
  for (int i = blockIdx.x * blockDim.x + threadIdx.x; i < n; i += gridDim.x * blockDim.x) {
    float yv = y[i], fv = bf2f(fb[i]);
    float sc = 1.f + fabsf(yv);
    float t0 = yv / sc, t1 = fv / sc;
    a0 += t0 * t0;
    a1 += t1 * t1;
  }
  __shared__ float r0[256], r1[256];
  int tid = threadIdx.x;
  r0[tid] = a0; r1[tid] = a1;
  __syncthreads();
  for (int off = 128; off > 0; off >>= 1) {
    if (tid < off) { r0[tid] += r0[tid + off]; r1[tid] += r1[tid + off]; }
    __syncthreads();
  }
  if (tid == 0) { atomicAdd(&s->d0s, r0[0]); atomicAdd(&s->d1s, r1[0]); }
}

__global__ void k_h0(Scal* s) {
  float d0 = sqrtf(s->d0s);    // 2-norm (jnp.linalg.norm), NOT rms
  float d1 = sqrtf(s->d1s);
  s->d0 = d0; s->d1 = d1;
  s->h0 = (d0 < 1e-5f || d1 < 1e-5f) ? 1e-6f : 0.01f * d0 / d1;
}

__global__ void k_d2(const float* __restrict__ y, const u16* __restrict__ fb,
                     const u16* __restrict__ f1h, int n, Scal* s) {
  float a = 0.f;
  for (int i = blockIdx.x * blockDim.x + threadIdx.x; i < n; i += gridDim.x * blockDim.x) {
    float v = (bf2f(f1h[i]) - bf2f(fb[i])) / (1.f + fabsf(y[i]));
    a += v * v;
  }
  __shared__ float r0[256];
  int tid = threadIdx.x;
  r0[tid] = a;
  __syncthreads();
  for (int off = 128; off > 0; off >>= 1) {
    if (tid < off) r0[tid] += r0[tid + off];
    __syncthreads();
  }
  if (tid == 0) atomicAdd(&s->d2s, r0[0]);
}

__global__ void k_dt(Scal* s) {
  float d2 = sqrtf(s->d2s) / s->h0;          // 2-norm / h0
  float h1 = (s->d1 <= 1e-15f && d2 <= 1e-15f)
                 ? fmaxf(1e-6f, s->h0 * 1e-3f)
                 : powf(0.01f / fmaxf(s->d1, d2), 1.0f / 6.0f);  // 1/(order+1)
  s->dt = fminf(100.f * s->h0, h1);
  s->t = 0.f;
  s->last_t = 0.f;
}

__global__ void k_step_begin(Scal* s) {
  s->run_flag = (s->t < 1.0f) && (s->dt > 0.f);
  s->accept_flag = 0;
  s->errs = 0.f;
}

__global__ void k_step_end(Scal* s) {
  if (!s->run_flag) { s->accept_flag = 0; return; }
  float ratio = sqrtf(s->errs / (float)NTOT);
  int acc = (ratio <= 1.0f);
  s->accept_flag = acc;
  float dfactor = (ratio < 1.f) ? 1.f : 0.2f;
  float factor = fminf(10.f, fmaxf(0.9f * powf(ratio, -0.2f), dfactor));
  float ndt = (ratio == 0.f) ? s->dt * 10.f : s->dt * factor;
  if (ndt < 0.f) ndt = 0.f;
  if (acc) { s->dt_saved = s->dt; s->last_t = s->t; s->t = s->t + s->dt; }
  s->dt = ndt;
}

__global__ void k_flip(Scal* s) {
  if (s->accept_flag) s->cur ^= 1;
}

// interp_fit + polyval at r=(1-last_t)/(t-last_t); ym aliases out; f0/f1 bf16
__global__ void k_final(const float* YA, const float* YB,
    const u16* __restrict__ f0s, const u16* __restrict__ f1s,
    float* out, int n, const Scal* s) {
  int cur = s->cur;
  const float* y1s = cur ? YB : YA;
  const float* y0s = cur ? YA : YB;
  float dt = s->dt_saved;
  float r = (1.0f - s->last_t) / (s->t - s->last_t);
  for (int i = blockIdx.x * blockDim.x + threadIdx.x; i < n; i += gridDim.x * blockDim.x) {
    float y0 = y0s[i], y1 = y1s[i], ym = out[i];
    float f0 = bf2f(f0s[i]), f1 = bf2f(f1s[i]);
    float a = 2.f * dt * (f1 - f0) - 8.f * (y1 + y0) + 16.f * ym;
    float b = dt * (5.f * f0 - 3.f * f1) + 18.f * y0 + 14.f * y1 - 32.f * ym;
    float c = dt * (f1 - 4.f * f0) - 11.f * y0 - 5.f * y1 + 16.f * ym;
    float d = dt * f0;
    out[i] = (((a * r + b) * r + c) * r + d) * r + y0;
  }
}

__global__ void k_debug_ws(float* __restrict__ out, int n, float mb) {
  for (int i = blockIdx.x * blockDim.x + threadIdx.x; i < n; i += gridDim.x * blockDim.x)
    out[i] = mb;
}

// ================================  driver  ==================================
extern "C" void kernel_launch(void* const* d_in, const int* in_sizes, int n_in,
                              void* d_out, int out_size, void* d_ws, size_t ws_size,
                              hipStream_t stream) {
  const float* x  = (const float*)d_in[0];
  const float* W1 = (const float*)d_in[1];   // [2049, 2048]
  const float* b1 = (const float*)d_in[2];
  const float* W2 = (const float*)d_in[3];   // [2048, 2048]
  const float* b2 = (const float*)d_in[4];
  float* out = (float*)d_out;
  const float* w1row = W1 + (size_t)2048 * 2048;  // time row (kept fp32)

  const size_t SZW = (size_t)2048 * 2048 * 2;  // 8 MB
  const size_t SZH = (size_t)NTOT * 2;         // 16 MB
  const size_t SZF = (size_t)NTOT * 4;         // 32 MB
  // W1T,W2T + YSH,YSL,HH,HL + YA,YB + FB,KB2,KB3,KB4,KB6
  const size_t NEED = 1024 + 2 * SZW + 4 * SZH + 2 * SZF + 5 * SZH;  // 224 MB

  if (ws_size < NEED) {
    k_debug_ws<<<2048, 256, 0, stream>>>(out, NTOT, (float)(ws_size >> 20));
    return;
  }

  char* base = (char*)d_ws;
  Scal* s = (Scal*)base;
  size_t o = 1024;
  auto take = [&](size_t bytes) { void* p = base + o; o += bytes; return p; };

  u16* W1T = (u16*)take(SZW); u16* W2T = (u16*)take(SZW);
  u16* YSH = (u16*)take(SZH); u16* YSL = (u16*)take(SZH);
  u16* HH  = (u16*)take(SZH); u16* HL  = (u16*)take(SZH);
  float* YA = (float*)take(SZF); float* YB = (float*)take(SZF);
  u16* FB  = (u16*)take(SZH); u16* KB2 = (u16*)take(SZH);
  u16* KB3 = (u16*)take(SZH); u16* KB4 = (u16*)take(SZH);
  u16* KB6 = (u16*)take(SZH);
  float* Mout = out;   // M -> ymid -> final, all in d_out

  const dim3 GG(1024), GB(256);
  const dim3 EG(2048), EB(256);

  // gemm1: ys @ W1, tanh epilogue -> HH/HL
  #define G1(tmode, alpha, flag) \
    gemm_fused<100><<<GG, GB, 0, stream>>>(YSH, YSL, W1T, b1, w1row, \
        tmode, alpha, 0.f, 0.f, 0.f, 0.f, \
        YA, YB, FB, KB2, KB3, KB4, KB6, Mout, HH, HL, s, flag)
  // gemm2: h @ W2, stage-specific epilogue
  #define G2(st, b0, b1c, b2c, bv, flag) \
    gemm_fused<st><<<GG, GB, 0, stream>>>(HH, HL, W2T, b2, nullptr, \
        0, 0.f, b0, b1c, b2c, bv, \
        YA, YB, FB, KB2, KB3, KB4, KB6, Mout, YSH, YSL, s, flag)

  // ---- setup ----
  transpose_hi<<<dim3(64, 64), dim3(32, 8), 0, stream>>>(W1, W1T, 2048, 2048);
  transpose_hi<<<dim3(64, 64), dim3(32, 8), 0, stream>>>(W2, W2T, 2048, 2048);
  k_init_scal<<<1, 1, 0, stream>>>(s);
  k_init_y<<<EG, EB, 0, stream>>>(x, YA, YSH, YSL, NTOT);

  // ---- Hairer initial step size ----
  G1(0, 0.f, 0); G2(10, 0.f, 0.f, 0.f, 0.f, 0);        // f0 = f(y0, 0) -> FB
  k_d01<<<1024, 256, 0, stream>>>(YA, FB, NTOT, s);
  k_h0<<<1, 1, 0, stream>>>(s);
  k_probe_ys<<<EG, EB, 0, stream>>>(YA, FB, YSH, YSL, NTOT, s);
  G1(1, 0.f, 0); G2(11, 0.f, 0.f, 0.f, 0.f, 0);        // f(y0+h0*f0, h0) -> KB4
  k_d2<<<1024, 256, 0, stream>>>(YA, FB, KB4, NTOT, s);
  k_dt<<<1, 1, 0, stream>>>(s);
  k_prep<<<EG, EB, 0, stream>>>(YA, YB, FB, KB3, KB4, Mout, YSH, YSL, NTOT / 4, s, 1);

  // ---- adaptive Dopri5 trials (unrolled, device-predicated) ----
  for (int st = 0; st < MAX_STEPS; ++st) {
    k_step_begin<<<1, 1, 0, stream>>>(s);
    // k2
    G1(0, 0.2f, 1);
    G2(0, (float)(3.0/40.0), 0.f, 0.f, (float)(9.0/40.0), 1);
    // k3
    G1(0, 0.3f, 1);
    G2(1, (float)(44.0/45.0), (float)(-56.0/15.0), 0.f, (float)(32.0/9.0), 1);
    // k4
    G1(0, 0.8f, 1);
    G2(2, (float)(19372.0/6561.0), (float)(-25360.0/2187.0),
       (float)(64448.0/6561.0), (float)(-212.0/729.0), 1);
    // k5 (hardcoded B5x; k5 overwrites k2 plane)
    G1(0, (float)(8.0/9.0), 1);
    G2(3, 0.f, 0.f, 0.f, 0.f, 1);
    // k6 (NY + k6 stored bf16)
    G1(0, 1.f, 1);
    G2(4, 0.f, 0.f, 0.f, 0.f, 1);
    // k7 (E/M recomputed from bf16 k's, fused error reduction)
    G1(0, 1.f, 1);
    G2(5, 0.f, 0.f, 0.f, 0.f, 1);

    k_step_end<<<1, 1, 0, stream>>>(s);
    k_prep<<<EG, EB, 0, stream>>>(YA, YB, FB, KB3, KB4, Mout, YSH, YSL, NTOT / 4, s, 0);
    k_flip<<<1, 1, 0, stream>>>(s);
  }

  // ---- interpolate to t=1 (ymid already in `out`; f0 in KB3, f1 in FB) ----
  k_final<<<EG, EB, 0, stream>>>(YA, YB, KB3, FB, out, NTOT, s);

  #undef G1
  #undef G2
}